// Round 3
// baseline (1983.566 us; speedup 1.0000x reference)
//
#include <hip/hip_runtime.h>
#include <hip/hip_fp16.h>
#include <hip/hip_bf16.h>

// shooting_model: B=16, H=W=512, L=10, MU=0.05, KS=7, SIGMA=2
// Numerics frozen (absmax 0.0156): f32 dynamics + f32 src/seg sampling,
// f16 phi displacement history, bf16 residual history.
// R13: diagnosis -- at VGPR=56 the compiler SANK the "batched" phase-1
// gathers to their uses, serializing ~9-18 memory round-trips per wave
// (the 44% VALUBusy plateau, insensitive to occupancy/LDS). Fix: pin the
// batches with sched_barrier(0): issue ALL phi corner loads -> barrier ->
// consume; materialize residual/ss bils + issue ALL their gathers ->
// barrier -> FMAs. Register-heavy by design (launch_bounds(256,2)).

namespace {
constexpr int W_ = 512, H_ = 512, L_ = 10;
constexpr int HW_ = W_ * H_;          // 1<<18
constexpr int N_  = 16 * HW_;         // 4194304
constexpr int G2_ = N_ / 512;         // 8192 blocks (512 px per block = 1 row)
constexpr float INVL = 0.1f;
constexpr float MU2L = 2.5e-4f;       // MU^2/L

__device__ __constant__ float GW[7] = {
    0.07015933f, 0.13107488f, 0.19071282f, 0.21610594f,
    0.19071282f, 0.13107488f, 0.07015933f};

struct BilL {                          // floor ints + weights
    int x0, y0;
    float w00, w01, w10, w11;
};
struct Bil {                           // + clamped float corner coords
    BilL l;
    float xc0, xc1, yc0, yc1;
};

__device__ __forceinline__ BilL mk_lite(float gx, float gy) {
    gx = fminf(fmaxf(gx, -1.0e9f), 1.0e9f);
    gy = fminf(fmaxf(gy, -1.0e9f), 1.0e9f);
    float x0f = floorf(gx), y0f = floorf(gy);
    float wx = gx - x0f, wy = gy - y0f;
    int x0 = (int)x0f, y0 = (int)y0f;
    float vx0 = ((unsigned)x0 < (unsigned)W_) ? 1.f : 0.f;
    float vx1 = ((unsigned)(x0 + 1) < (unsigned)W_) ? 1.f : 0.f;
    float vy0 = ((unsigned)y0 < (unsigned)H_) ? 1.f : 0.f;
    float vy1 = ((unsigned)(y0 + 1) < (unsigned)H_) ? 1.f : 0.f;
    BilL b;
    b.x0 = x0; b.y0 = y0;
    b.w00 = (1.f - wx) * (1.f - wy) * vx0 * vy0;
    b.w01 = wx * (1.f - wy) * vx1 * vy0;
    b.w10 = (1.f - wx) * wy * vx0 * vy1;
    b.w11 = wx * wy * vx1 * vy1;
    return b;
}

__device__ __forceinline__ Bil mk_full(float gx, float gy) {
    Bil b;
    b.l = mk_lite(gx, gy);
    int xc0 = min(max(b.l.x0, 0), W_ - 1), xc1 = min(max(b.l.x0 + 1, 0), W_ - 1);
    int yc0 = min(max(b.l.y0, 0), H_ - 1), yc1 = min(max(b.l.y0 + 1, 0), H_ - 1);
    b.xc0 = (float)xc0; b.xc1 = (float)xc1;
    b.yc0 = (float)yc0; b.yc1 = (float)yc1;
    return b;
}

__device__ __forceinline__ void gidx(const BilL& b, int& i00, int& i01,
                                     int& i10, int& i11) {
    int xc0 = min(max(b.x0, 0), W_ - 1), xc1 = min(max(b.x0 + 1, 0), W_ - 1);
    int yc0 = min(max(b.y0, 0), H_ - 1), yc1 = min(max(b.y0 + 1, 0), H_ - 1);
    i00 = yc0 * W_ + xc0; i01 = yc0 * W_ + xc1;
    i10 = yc1 * W_ + xc0; i11 = yc1 * W_ + xc1;
}

__device__ __forceinline__ float2 upk(unsigned u) {
    __half2 h; *reinterpret_cast<unsigned*>(&h) = u;
    return __half22float2(h);
}
__device__ __forceinline__ unsigned pkh(float a, float b) {
    __half2 h = __floats2half2_rn(a, b);
    return *reinterpret_cast<unsigned*>(&h);
}
__device__ __forceinline__ unsigned short f2bf(float f) {
    unsigned u = __float_as_uint(f);
    return (unsigned short)((u + 0x7fffu + ((u >> 16) & 1u)) >> 16);
}
__device__ __forceinline__ float bfu(unsigned u) {   // zext bf16 -> f32
    return __uint_as_float(u << 16);
}

// pack src/seg f32 -> interleaved float2 (exact copy)
__global__ __launch_bounds__(256) void k_pack2(const float* __restrict__ src,
                                               const float* __restrict__ seg,
                                               float2* __restrict__ out) {
    int idx = blockIdx.x * 256 + threadIdx.x;
    out[idx] = make_float2(src[idx], seg[idx]);
}

// Fused dynamics: sobel(image)*(-r) -> separable 7x7 gaussian -> v;
// f = div(r*v)/L; rnext = r - f (f32 opt + bf16); phi = v/L (half2).
__global__ __launch_bounds__(256) void k_A(const float* __restrict__ img,
                                           const float* __restrict__ rin,
                                           float* __restrict__ rnext_f,
                                           __hip_bfloat16* __restrict__ rnext_b,
                                           __half2* __restrict__ phi_new) {
    __shared__ float sI[26][43];
    __shared__ float sR[24][41];
    __shared__ float sS[2][24][41];
    __shared__ float sTH[2][24][35];
    const int t = threadIdx.x;
    const int x0 = blockIdx.x * 32, y0 = blockIdx.y * 16, b = blockIdx.z;
    const float* ip = img + (size_t)b * HW_;
    const float* rp = rin + (size_t)b * HW_;
    for (int u = t; u < 26 * 42; u += 256) {
        int r = u / 42, c = u % 42;
        int gy = min(max(y0 - 5 + r, 0), H_ - 1);
        int gx = min(max(x0 - 5 + c, 0), W_ - 1);
        sI[r][c] = ip[gy * W_ + gx];
    }
    for (int u = t; u < 24 * 40; u += 256) {
        int r = u / 40, c = u % 40;
        int gy = y0 - 4 + r, gx = x0 - 4 + c;
        sR[r][c] = ((unsigned)gy < (unsigned)H_ && (unsigned)gx < (unsigned)W_)
                 ? rp[gy * W_ + gx] : 0.f;
    }
    __syncthreads();
    for (int u = t; u < 24 * 40; u += 256) {   // s = -r * sobel(img)
        int r = u / 40, c = u % 40;
        float a00 = sI[r][c],     a01 = sI[r][c + 1],     a02 = sI[r][c + 2];
        float a10 = sI[r + 1][c],                          a12 = sI[r + 1][c + 2];
        float a20 = sI[r + 2][c], a21 = sI[r + 2][c + 1], a22 = sI[r + 2][c + 2];
        float gxv = ((a02 - a00) + 2.f * (a12 - a10) + (a22 - a20)) * 0.125f;
        float gyv = ((a20 - a00) + 2.f * (a21 - a01) + (a22 - a02)) * 0.125f;
        float rv = sR[r][c];
        sS[0][r][c] = -rv * gxv;
        sS[1][r][c] = -rv * gyv;
    }
    __syncthreads();
    for (int u = t; u < 24 * 34; u += 256) {   // th = h-blur(s)
        int r = u / 34, c = u % 34;
        float t0 = 0.f, t1 = 0.f;
#pragma unroll
        for (int k = 0; k < 7; k++) {
            t0 += GW[k] * sS[0][r][c + k];
            t1 += GW[k] * sS[1][r][c + k];
        }
        sTH[0][r][c] = t0; sTH[1][r][c] = t1;
    }
    __syncthreads();
    const int tx = t & 15, ty = t >> 4;        // 2 px/thread in x
    const int y = y0 + ty;
    float rn2[2]; unsigned ph2[2];
#pragma unroll
    for (int px = 0; px < 2; px++) {
        const int lx = tx * 2 + px;
        const int x = x0 + lx;
        auto V = [&](int ch, int dy, int dx) -> float {
            float s = 0.f;
#pragma unroll
            for (int k = 0; k < 7; k++) s += GW[k] * sTH[ch][ty + 1 + dy + k][lx + 1 + dx];
            return s;
        };
        auto Wt = [&](int ch, int dy, int dx) -> float {
            int yy = y + dy, xx = x + dx;
            if ((unsigned)yy >= (unsigned)H_ || (unsigned)xx >= (unsigned)W_) return 0.f;
            return sR[ty + 4 + dy][lx + 4 + dx] * V(ch, dy, dx);
        };
        float f = (Wt(0, -1, 1) - Wt(0, -1, -1)) + 2.f * (Wt(0, 0, 1) - Wt(0, 0, -1))
                + (Wt(0, 1, 1) - Wt(0, 1, -1))
                + (Wt(1, 1, -1) - Wt(1, -1, -1)) + 2.f * (Wt(1, 1, 0) - Wt(1, -1, 0))
                + (Wt(1, 1, 1) - Wt(1, -1, 1));
        f *= 0.0125f;                          // (1/8 div-kernel) * (1/L)
        rn2[px] = sR[ty + 4][lx + 4] - f;
        ph2[px] = pkh(V(0, 0, 0) * INVL, V(1, 0, 0) * INVL);
    }
    int idx0 = b * HW_ + y * W_ + x0 + tx * 2; // even
    if (rnext_f)
        *reinterpret_cast<float2*>(rnext_f + idx0) = make_float2(rn2[0], rn2[1]);
    unsigned bpair = (unsigned)f2bf(rn2[0]) | ((unsigned)f2bf(rn2[1]) << 16);
    *reinterpret_cast<unsigned*>(reinterpret_cast<unsigned short*>(rnext_b) + idx0) = bpair;
    *reinterpret_cast<uint2*>(phi_new + idx0) = make_uint2(ph2[0], ph2[1]);
}

struct StepArgs {
    const __half2* def;
    const __half2* oldp[9];
    __half2* newp[9];
    const __half2* pre[8];
    const float2* ss2;                  // interleaved f32 src/seg
    const float* rn_f;                  // null -> use rn_b
    const __hip_bfloat16* rn_b;
    const __hip_bfloat16* resb;
    float* out;
    int npre, i;
};

// 2 px/thread, one image row per block. Loads batched and PINNED with
// sched_barrier(0) so all corner gathers of a phase are in flight before
// any consumption (defeats compiler load-sinking / per-plane serialization).
template <int NB, bool DOOUT, bool WR>
__global__ __launch_bounds__(256, 2) void k_step(StepArgs A) {
    constexpr int NBa = NB > 0 ? NB : 1;
    const int tid = threadIdx.x;
    int phys = blockIdx.x;
    // XCD-contiguous swizzle: phys%8 -> XCD; give each XCD a contiguous 1/8.
    int logical = ((phys & 7) * (G2_ / 8)) + (phys >> 3);
    int tid2 = logical * 256 + tid;           // pixel-pair index
    int p0 = tid2 * 2;
    int x = p0 & (W_ - 1);                    // even; pair = x, x+1 (same row)
    int y = (p0 >> 9) & (H_ - 1);
    int b = p0 >> 18;
    size_t base = (size_t)b * HW_;

    // independent early loads
    float s0 = 0.f, s1 = 0.f;
    if (DOOUT) {
        if (A.rn_f) {
            float2 rv = reinterpret_cast<const float2*>(A.rn_f)[tid2];
            s0 = rv.x; s1 = rv.y;
        } else {
            s0 = __bfloat162float(A.rn_b[p0]);
            s1 = __bfloat162float(A.rn_b[p0 + 1]);
        }
    }
    uint2 dv = reinterpret_cast<const uint2*>(A.def)[tid2];
    float2 d0 = upk(dv.x), d1 = upk(dv.y);
    Bil bw0 = mk_full((float)x - d0.x, (float)y - d0.y);
    Bil bw1 = mk_full((float)(x + 1) - d1.x, (float)y - d1.y);
    int a00, a01, a10, a11, e00, e01, e10, e11;
    gidx(bw0.l, a00, a01, a10, a11);
    gidx(bw1.l, e00, e01, e10, e11);

    // ---- Phase 1: ALL phi-plane corner loads, pinned as one batch ----
    unsigned c0[NBa][4], c1[NBa][4];
#pragma unroll
    for (int t = 0; t < NB; t++) {
        const unsigned* p = reinterpret_cast<const unsigned*>(A.oldp[t] + base);
        c0[t][0] = p[a00]; c0[t][1] = p[a01];
        c0[t][2] = p[a10]; c0[t][3] = p[a11];
        c1[t][0] = p[e00]; c1[t][1] = p[e01];
        c1[t][2] = p[e10]; c1[t][3] = p[e11];
    }
    __builtin_amdgcn_sched_barrier(0);

    // ---- Phase 2: warped coords; store warped planes ----
    float wox0[NBa], woy0[NBa], wox1[NBa], woy1[NBa];
#pragma unroll
    for (int t = 0; t < NB; t++) {
        float2 s00 = upk(c0[t][0]), s01 = upk(c0[t][1]);
        float2 s10 = upk(c0[t][2]), s11 = upk(c0[t][3]);
        wox0[t] = bw0.l.w00 * (bw0.xc0 - s00.x) + bw0.l.w01 * (bw0.xc1 - s01.x)
                + bw0.l.w10 * (bw0.xc0 - s10.x) + bw0.l.w11 * (bw0.xc1 - s11.x);
        woy0[t] = bw0.l.w00 * (bw0.yc0 - s00.y) + bw0.l.w01 * (bw0.yc0 - s01.y)
                + bw0.l.w10 * (bw0.yc1 - s10.y) + bw0.l.w11 * (bw0.yc1 - s11.y);
        float2 t00 = upk(c1[t][0]), t01 = upk(c1[t][1]);
        float2 t10 = upk(c1[t][2]), t11 = upk(c1[t][3]);
        wox1[t] = bw1.l.w00 * (bw1.xc0 - t00.x) + bw1.l.w01 * (bw1.xc1 - t01.x)
                + bw1.l.w10 * (bw1.xc0 - t10.x) + bw1.l.w11 * (bw1.xc1 - t11.x);
        woy1[t] = bw1.l.w00 * (bw1.yc0 - t00.y) + bw1.l.w01 * (bw1.yc0 - t01.y)
                + bw1.l.w10 * (bw1.yc1 - t10.y) + bw1.l.w11 * (bw1.yc1 - t11.y);
        if (WR) {
            uint2 st;
            st.x = pkh((float)x - wox0[t],       (float)y - woy0[t]);
            st.y = pkh((float)(x + 1) - wox1[t], (float)y - woy1[t]);
            reinterpret_cast<uint2*>(A.newp[t])[tid2] = st;
        }
    }

    if (DOOUT) {
        float si0 = 0.f, ss0 = 0.f, si1 = 0.f, ss1 = 0.f;
        const float2* ssp = A.ss2 + base;

        // pre planes (warped in earlier batches): serial exact path
        for (int j = 0; j < A.npre; j++) {
            uint2 pv = reinterpret_cast<const uint2*>(A.pre[j])[tid2];
            float2 e0 = upk(pv.x), e1 = upk(pv.y);
            BilL q0 = mk_lite((float)x - e0.x, (float)y - e0.y);
            BilL q1 = mk_lite((float)(x + 1) - e1.x, (float)y - e1.y);
            int i00, i01, i10, i11;
            if (j == 0) {
                gidx(q0, i00, i01, i10, i11);
                float2 c00 = ssp[i00], c01 = ssp[i01], c10 = ssp[i10], c11 = ssp[i11];
                si0 = c00.x * q0.w00 + c01.x * q0.w01 + c10.x * q0.w10 + c11.x * q0.w11;
                ss0 = c00.y * q0.w00 + c01.y * q0.w01 + c10.y * q0.w10 + c11.y * q0.w11;
                gidx(q1, i00, i01, i10, i11);
                float2 d00 = ssp[i00], d01 = ssp[i01], d10 = ssp[i10], d11 = ssp[i11];
                si1 = d00.x * q1.w00 + d01.x * q1.w01 + d10.x * q1.w10 + d11.x * q1.w11;
                ss1 = d00.y * q1.w00 + d01.y * q1.w01 + d10.y * q1.w10 + d11.y * q1.w11;
            } else {
                const __hip_bfloat16* rp = A.resb + (size_t)(j - 1) * N_ + base;
                gidx(q0, i00, i01, i10, i11);
                s0 += __bfloat162float(rp[i00]) * q0.w00 + __bfloat162float(rp[i01]) * q0.w01
                    + __bfloat162float(rp[i10]) * q0.w10 + __bfloat162float(rp[i11]) * q0.w11;
                gidx(q1, i00, i01, i10, i11);
                s1 += __bfloat162float(rp[i00]) * q1.w00 + __bfloat162float(rp[i01]) * q1.w01
                    + __bfloat162float(rp[i10]) * q1.w10 + __bfloat162float(rp[i11]) * q1.w11;
            }
        }

        // ---- Phase 3: bils + ALL residual/ss corner loads, pinned ----
        BilL q0a[NBa], q1a[NBa];
        unsigned rc0[NBa][4], rc1[NBa][4];   // residual corners (planes npre+t>0)
        float2 sc0[4], sc1[4];               // ss corners (npre+t==0)
        unsigned fc0[4], fc1[4];             // final residual corners (i>0)
        float2 fsc0[4], fsc1[4];             // final ss corners (i==0)
#pragma unroll
        for (int t = 0; t < NB; t++) {
            q0a[t] = mk_lite(wox0[t], woy0[t]);
            q1a[t] = mk_lite(wox1[t], woy1[t]);
            int i00, i01, i10, i11;
            if (t == 0 && A.npre == 0) {
                gidx(q0a[t], i00, i01, i10, i11);
                sc0[0] = ssp[i00]; sc0[1] = ssp[i01]; sc0[2] = ssp[i10]; sc0[3] = ssp[i11];
                gidx(q1a[t], i00, i01, i10, i11);
                sc1[0] = ssp[i00]; sc1[1] = ssp[i01]; sc1[2] = ssp[i10]; sc1[3] = ssp[i11];
            } else {
                const unsigned short* rp = reinterpret_cast<const unsigned short*>(
                    A.resb + (size_t)(A.npre + t - 1) * N_ + base);
                gidx(q0a[t], i00, i01, i10, i11);
                rc0[t][0] = rp[i00]; rc0[t][1] = rp[i01];
                rc0[t][2] = rp[i10]; rc0[t][3] = rp[i11];
                gidx(q1a[t], i00, i01, i10, i11);
                rc1[t][0] = rp[i00]; rc1[t][1] = rp[i01];
                rc1[t][2] = rp[i10]; rc1[t][3] = rp[i11];
            }
        }
        if (A.i == 0) {
            fsc0[0] = ssp[a00]; fsc0[1] = ssp[a01]; fsc0[2] = ssp[a10]; fsc0[3] = ssp[a11];
            fsc1[0] = ssp[e00]; fsc1[1] = ssp[e01]; fsc1[2] = ssp[e10]; fsc1[3] = ssp[e11];
        } else {
            const unsigned short* rp = reinterpret_cast<const unsigned short*>(
                A.resb + (size_t)(A.i - 1) * N_ + base);
            fc0[0] = rp[a00]; fc0[1] = rp[a01]; fc0[2] = rp[a10]; fc0[3] = rp[a11];
            fc1[0] = rp[e00]; fc1[1] = rp[e01]; fc1[2] = rp[e10]; fc1[3] = rp[e11];
        }
        __builtin_amdgcn_sched_barrier(0);

        // ---- Phase 4: consume in exact original order ----
#pragma unroll
        for (int t = 0; t < NB; t++) {
            if (t == 0 && A.npre == 0) {
                const BilL& q0 = q0a[t];
                si0 = sc0[0].x * q0.w00 + sc0[1].x * q0.w01
                    + sc0[2].x * q0.w10 + sc0[3].x * q0.w11;
                ss0 = sc0[0].y * q0.w00 + sc0[1].y * q0.w01
                    + sc0[2].y * q0.w10 + sc0[3].y * q0.w11;
                const BilL& q1 = q1a[t];
                si1 = sc1[0].x * q1.w00 + sc1[1].x * q1.w01
                    + sc1[2].x * q1.w10 + sc1[3].x * q1.w11;
                ss1 = sc1[0].y * q1.w00 + sc1[1].y * q1.w01
                    + sc1[2].y * q1.w10 + sc1[3].y * q1.w11;
            } else {
                const BilL& q0 = q0a[t];
                s0 += bfu(rc0[t][0]) * q0.w00 + bfu(rc0[t][1]) * q0.w01
                    + bfu(rc0[t][2]) * q0.w10 + bfu(rc0[t][3]) * q0.w11;
                const BilL& q1 = q1a[t];
                s1 += bfu(rc1[t][0]) * q1.w00 + bfu(rc1[t][1]) * q1.w01
                    + bfu(rc1[t][2]) * q1.w10 + bfu(rc1[t][3]) * q1.w11;
            }
        }
        if (A.i == 0) {
            si0 = fsc0[0].x * bw0.l.w00 + fsc0[1].x * bw0.l.w01
                + fsc0[2].x * bw0.l.w10 + fsc0[3].x * bw0.l.w11;
            ss0 = fsc0[0].y * bw0.l.w00 + fsc0[1].y * bw0.l.w01
                + fsc0[2].y * bw0.l.w10 + fsc0[3].y * bw0.l.w11;
            si1 = fsc1[0].x * bw1.l.w00 + fsc1[1].x * bw1.l.w01
                + fsc1[2].x * bw1.l.w10 + fsc1[3].x * bw1.l.w11;
            ss1 = fsc1[0].y * bw1.l.w00 + fsc1[1].y * bw1.l.w01
                + fsc1[2].y * bw1.l.w10 + fsc1[3].y * bw1.l.w11;
        } else {
            s0 += bfu(fc0[0]) * bw0.l.w00 + bfu(fc0[1]) * bw0.l.w01
                + bfu(fc0[2]) * bw0.l.w10 + bfu(fc0[3]) * bw0.l.w11;
            s1 += bfu(fc1[0]) * bw1.l.w00 + bfu(fc1[1]) * bw1.l.w01
                + bfu(fc1[2]) * bw1.l.w10 + bfu(fc1[3]) * bw1.l.w11;
        }
        float2 o = make_float2(si0 + s0 * MU2L * ss0, si1 + s1 * MU2L * ss1);
        reinterpret_cast<float2*>(A.out)[tid2] = o;
    }
}

// diagnostic fallback (normalized error 0.96 signature == ws too small)
__global__ __launch_bounds__(256) void k_copy(const float* __restrict__ a,
                                              float* __restrict__ o) {
    int idx = blockIdx.x * 256 + threadIdx.x;
    o[idx] = a[idx];
}

void dispatch_step(int nb, bool doout, bool wr, const StepArgs& A,
                   dim3 g, dim3 blk, hipStream_t st) {
#define CASE(NBv)                                                          \
    case NBv:                                                              \
        if (doout) {                                                       \
            if (wr) hipLaunchKernelGGL((k_step<NBv, true, true>), g, blk, 0, st, A); \
            else    hipLaunchKernelGGL((k_step<NBv, true, false>), g, blk, 0, st, A);\
        } else      hipLaunchKernelGGL((k_step<NBv, false, true>), g, blk, 0, st, A);\
        break;
    switch (nb) {
        CASE(0) CASE(1) CASE(2) CASE(3) CASE(4)
        CASE(5) CASE(6) CASE(7) CASE(8) CASE(9)
        default: break;
    }
#undef CASE
}

} // namespace

extern "C" void kernel_launch(void* const* d_in, const int* in_sizes, int n_in,
                              void* d_out, int out_size, void* d_ws, size_t ws_size,
                              hipStream_t stream) {
    const float* source = (const float*)d_in[0];
    const float* z0     = (const float*)d_in[1];
    const float* seg    = (const float*)d_in[2];
    float* out = (float*)d_out;

    const size_t UNIT = (size_t)N_ * 4;          // 16 MiB
    const size_t ARENA = (size_t)N_ * 2 * 10;    // 80 MiB bf16 residuals
    dim3 blk(256), g1(N_ / 256), g2(G2_), gA(16, 32, 16);

    int U = (ws_size > ARENA) ? (int)((ws_size - ARENA) / UNIT) : 0;
    if (U < 11) { hipLaunchKernelGGL(k_copy, g1, blk, 0, stream, source, out); return; }
    if (U > 16) U = 16;

    char* basep = (char*)d_ws;
    __hip_bfloat16* arena = (__hip_bfloat16*)(basep + (size_t)U * UNIT);
    float2* ss2 = (float2*)basep;                // units 0-1: packed src/seg (f32)

    // free pool: ws units 2..U-1, plus src/seg/z0 buffers after step 0.
    char* pool[24]; int top = 0;
    for (int u = U - 1; u >= 2; u--) pool[top++] = basep + (size_t)u * UNIT;

    char* phi[10];
    char* rn = nullptr;                          // r_{i+1} f32 plane

    // ---- step 0 ----
    hipLaunchKernelGGL(k_pack2, g1, blk, 0, stream, source, seg, ss2);
    phi[0] = pool[--top];
    rn     = pool[--top];
    hipLaunchKernelGGL(k_A, gA, blk, 0, stream, source, z0, (float*)rn,
                       arena, (__half2*)phi[0]);
    pool[top++] = (char*)source;                 // inputs dead (harness restores)
    pool[top++] = (char*)seg;
    pool[top++] = (char*)z0;
    {
        StepArgs A{};
        A.def = (const __half2*)phi[0];
        A.ss2 = ss2;
        A.rn_f = (const float*)rn;
        A.rn_b = arena + (size_t)9 * N_; A.resb = arena;
        A.out = out; A.npre = 0; A.i = 0;
        dispatch_step(0, true, true, A, g2, blk, stream);
    }

    // ---- steps 1..9 ----
    for (int i = 1; i < L_; i++) {
        char* nphi = pool[--top];
        char* nrn  = (i <= 8) ? pool[--top] : nullptr;
        hipLaunchKernelGGL(k_A, gA, blk, 0, stream, (const float*)out,
                           (const float*)rn, (float*)nrn,
                           arena + (size_t)i * N_, (__half2*)nphi);
        pool[top++] = rn;                        // r_i f32 dead
        rn = nrn;
        phi[i] = nphi;

        int j0 = 0, remaining = i;
        while (remaining > 0) {
            bool last = (i == 9) || (top >= remaining);
            int nb = (i == 9) ? 9 : (last ? remaining : (top < remaining - 1 ? top
                                                                : remaining - 1));
            if (nb < 1) nb = 1;
            StepArgs A{};
            A.def = (const __half2*)phi[i];
            char* nd[9];
            bool wr = (i != 9);
            for (int t = 0; t < nb; t++) {
                A.oldp[t] = (const __half2*)phi[j0 + t];
                if (wr) { nd[t] = pool[--top]; A.newp[t] = (__half2*)nd[t]; }
            }
            for (int t = 0; t < j0; t++) A.pre[t] = (const __half2*)phi[t];
            A.ss2 = ss2;
            A.rn_f = (i <= 8) ? (const float*)rn : nullptr;
            A.rn_b = arena + (size_t)9 * N_;
            A.resb = arena;
            A.out = out; A.npre = j0; A.i = i;
            dispatch_step(nb, last, wr, A, g2, blk, stream);
            if (wr) {
                for (int t = 0; t < nb; t++) {
                    pool[top++] = phi[j0 + t];
                    phi[j0 + t] = nd[t];
                }
            }
            j0 += nb; remaining -= nb;
        }
    }
    (void)in_sizes; (void)n_in; (void)out_size;
}

// Round 5
// 901.841 us; speedup vs baseline: 2.1995x; 2.1995x over previous
//
#include <hip/hip_runtime.h>
#include <hip/hip_fp16.h>
#include <hip/hip_bf16.h>

// shooting_model: B=16, H=W=512, L=10, MU=0.05, KS=7, SIGMA=2
// R15: algebraic restructure. Output only needs residuals_sum; maintain
// B_i = r_{i+1}@px + AW_i where AW_{i+1} = bilerp(B_i, def_{i+1}) (exact up
// to interp-commutation, which enters output scaled by MU^2/L = 2.5e-4 and
// displacements are ~1e-3 px). Kills the 9-plane phi/residual history:
// per step only phi0 (half2) is re-warped and one f32 plane B is resampled.
// k_step: 12 scattered corner loads/px total (phi0, B, ss2) vs ~76 before.
// bf16 residual arena deleted (k_A loses a write stream). B chain in f32
// (replaces bf16 sampling -> some quantization error removed).
// Workspace: 10 units of 16 MiB (ws has >=11 + 80MiB arena worth; fits).

namespace {
constexpr int W_ = 512, H_ = 512, L_ = 10;
constexpr int HW_ = W_ * H_;          // 1<<18
constexpr int N_  = 16 * HW_;         // 4194304
constexpr int G2_ = N_ / 512;         // 8192 blocks (512 px per block = 1 row)
constexpr float INVL = 0.1f;
constexpr float MU2L = 2.5e-4f;       // MU^2/L

__device__ __constant__ float GW[7] = {
    0.07015933f, 0.13107488f, 0.19071282f, 0.21610594f,
    0.19071282f, 0.13107488f, 0.07015933f};

struct BilL {                          // floor ints + weights
    int x0, y0;
    float w00, w01, w10, w11;
};
struct Bil {                           // + clamped float corner coords
    BilL l;
    float xc0, xc1, yc0, yc1;
};

__device__ __forceinline__ BilL mk_lite(float gx, float gy) {
    gx = fminf(fmaxf(gx, -1.0e9f), 1.0e9f);
    gy = fminf(fmaxf(gy, -1.0e9f), 1.0e9f);
    float x0f = floorf(gx), y0f = floorf(gy);
    float wx = gx - x0f, wy = gy - y0f;
    int x0 = (int)x0f, y0 = (int)y0f;
    float vx0 = ((unsigned)x0 < (unsigned)W_) ? 1.f : 0.f;
    float vx1 = ((unsigned)(x0 + 1) < (unsigned)W_) ? 1.f : 0.f;
    float vy0 = ((unsigned)y0 < (unsigned)H_) ? 1.f : 0.f;
    float vy1 = ((unsigned)(y0 + 1) < (unsigned)H_) ? 1.f : 0.f;
    BilL b;
    b.x0 = x0; b.y0 = y0;
    b.w00 = (1.f - wx) * (1.f - wy) * vx0 * vy0;
    b.w01 = wx * (1.f - wy) * vx1 * vy0;
    b.w10 = (1.f - wx) * wy * vx0 * vy1;
    b.w11 = wx * wy * vx1 * vy1;
    return b;
}

__device__ __forceinline__ Bil mk_full(float gx, float gy) {
    Bil b;
    b.l = mk_lite(gx, gy);
    int xc0 = min(max(b.l.x0, 0), W_ - 1), xc1 = min(max(b.l.x0 + 1, 0), W_ - 1);
    int yc0 = min(max(b.l.y0, 0), H_ - 1), yc1 = min(max(b.l.y0 + 1, 0), H_ - 1);
    b.xc0 = (float)xc0; b.xc1 = (float)xc1;
    b.yc0 = (float)yc0; b.yc1 = (float)yc1;
    return b;
}

__device__ __forceinline__ void gidx(const BilL& b, int& i00, int& i01,
                                     int& i10, int& i11) {
    int xc0 = min(max(b.x0, 0), W_ - 1), xc1 = min(max(b.x0 + 1, 0), W_ - 1);
    int yc0 = min(max(b.y0, 0), H_ - 1), yc1 = min(max(b.y0 + 1, 0), H_ - 1);
    i00 = yc0 * W_ + xc0; i01 = yc0 * W_ + xc1;
    i10 = yc1 * W_ + xc0; i11 = yc1 * W_ + xc1;
}

__device__ __forceinline__ float2 upk(unsigned u) {
    __half2 h; *reinterpret_cast<unsigned*>(&h) = u;
    return __half22float2(h);
}
__device__ __forceinline__ unsigned pkh(float a, float b) {
    __half2 h = __floats2half2_rn(a, b);
    return *reinterpret_cast<unsigned*>(&h);
}

// phi buffers store DISPLACEMENT (id - phi_abs) as half2, like def.
// Warp: abs = sum w*(corner_clamped - disp) ; new disp = x - abs.
__device__ __forceinline__ void warp_from(unsigned v00, unsigned v01,
                                          unsigned v10, unsigned v11,
                                          const Bil& bw, float& wxo, float& wyo) {
    float2 s00 = upk(v00), s01 = upk(v01), s10 = upk(v10), s11 = upk(v11);
    wxo = bw.l.w00 * (bw.xc0 - s00.x) + bw.l.w01 * (bw.xc1 - s01.x)
        + bw.l.w10 * (bw.xc0 - s10.x) + bw.l.w11 * (bw.xc1 - s11.x);
    wyo = bw.l.w00 * (bw.yc0 - s00.y) + bw.l.w01 * (bw.yc0 - s01.y)
        + bw.l.w10 * (bw.yc1 - s10.y) + bw.l.w11 * (bw.yc1 - s11.y);
}

// pack src/seg f32 -> interleaved float2 (exact copy)
__global__ __launch_bounds__(256) void k_pack2(const float* __restrict__ src,
                                               const float* __restrict__ seg,
                                               float2* __restrict__ out) {
    int idx = blockIdx.x * 256 + threadIdx.x;
    out[idx] = make_float2(src[idx], seg[idx]);
}

// Fused dynamics: sobel(image)*(-r) -> separable 7x7 gaussian -> v;
// f = div(r*v)/L; rnext = r - f (f32); phi = v/L (half2 displacement).
__global__ __launch_bounds__(256) void k_A(const float* __restrict__ img,
                                           const float* __restrict__ rin,
                                           float* __restrict__ rnext_f,
                                           __half2* __restrict__ phi_new) {
    __shared__ float sI[26][43];
    __shared__ float sR[24][41];
    __shared__ float sS[2][24][41];
    __shared__ float sTH[2][24][35];
    const int t = threadIdx.x;
    const int x0 = blockIdx.x * 32, y0 = blockIdx.y * 16, b = blockIdx.z;
    const float* ip = img + (size_t)b * HW_;
    const float* rp = rin + (size_t)b * HW_;
    for (int u = t; u < 26 * 42; u += 256) {
        int r = u / 42, c = u % 42;
        int gy = min(max(y0 - 5 + r, 0), H_ - 1);
        int gx = min(max(x0 - 5 + c, 0), W_ - 1);
        sI[r][c] = ip[gy * W_ + gx];
    }
    for (int u = t; u < 24 * 40; u += 256) {
        int r = u / 40, c = u % 40;
        int gy = y0 - 4 + r, gx = x0 - 4 + c;
        sR[r][c] = ((unsigned)gy < (unsigned)H_ && (unsigned)gx < (unsigned)W_)
                 ? rp[gy * W_ + gx] : 0.f;
    }
    __syncthreads();
    for (int u = t; u < 24 * 40; u += 256) {   // s = -r * sobel(img)
        int r = u / 40, c = u % 40;
        float a00 = sI[r][c],     a01 = sI[r][c + 1],     a02 = sI[r][c + 2];
        float a10 = sI[r + 1][c],                          a12 = sI[r + 1][c + 2];
        float a20 = sI[r + 2][c], a21 = sI[r + 2][c + 1], a22 = sI[r + 2][c + 2];
        float gxv = ((a02 - a00) + 2.f * (a12 - a10) + (a22 - a20)) * 0.125f;
        float gyv = ((a20 - a00) + 2.f * (a21 - a01) + (a22 - a02)) * 0.125f;
        float rv = sR[r][c];
        sS[0][r][c] = -rv * gxv;
        sS[1][r][c] = -rv * gyv;
    }
    __syncthreads();
    for (int u = t; u < 24 * 34; u += 256) {   // th = h-blur(s)
        int r = u / 34, c = u % 34;
        float t0 = 0.f, t1 = 0.f;
#pragma unroll
        for (int k = 0; k < 7; k++) {
            t0 += GW[k] * sS[0][r][c + k];
            t1 += GW[k] * sS[1][r][c + k];
        }
        sTH[0][r][c] = t0; sTH[1][r][c] = t1;
    }
    __syncthreads();
    const int tx = t & 15, ty = t >> 4;        // 2 px/thread in x
    const int y = y0 + ty;
    float rn2[2]; unsigned ph2[2];
#pragma unroll
    for (int px = 0; px < 2; px++) {
        const int lx = tx * 2 + px;
        const int x = x0 + lx;
        auto V = [&](int ch, int dy, int dx) -> float {
            float s = 0.f;
#pragma unroll
            for (int k = 0; k < 7; k++) s += GW[k] * sTH[ch][ty + 1 + dy + k][lx + 1 + dx];
            return s;
        };
        auto Wt = [&](int ch, int dy, int dx) -> float {
            int yy = y + dy, xx = x + dx;
            if ((unsigned)yy >= (unsigned)H_ || (unsigned)xx >= (unsigned)W_) return 0.f;
            return sR[ty + 4 + dy][lx + 4 + dx] * V(ch, dy, dx);
        };
        float f = (Wt(0, -1, 1) - Wt(0, -1, -1)) + 2.f * (Wt(0, 0, 1) - Wt(0, 0, -1))
                + (Wt(0, 1, 1) - Wt(0, 1, -1))
                + (Wt(1, 1, -1) - Wt(1, -1, -1)) + 2.f * (Wt(1, 1, 0) - Wt(1, -1, 0))
                + (Wt(1, 1, 1) - Wt(1, -1, 1));
        f *= 0.0125f;                          // (1/8 div-kernel) * (1/L)
        rn2[px] = sR[ty + 4][lx + 4] - f;
        ph2[px] = pkh(V(0, 0, 0) * INVL, V(1, 0, 0) * INVL);
    }
    int idx0 = b * HW_ + y * W_ + x0 + tx * 2; // even
    *reinterpret_cast<float2*>(rnext_f + idx0) = make_float2(rn2[0], rn2[1]);
    *reinterpret_cast<uint2*>(phi_new + idx0) = make_uint2(ph2[0], ph2[1]);
}

struct StepArgs {
    const uint2* def;                   // def_i displacement (half2/px)
    const unsigned* p0_old;             // phi0 displacement (half2/px)
    unsigned* p0_new;
    const float* Bold;                  // B_{i-1} f32 plane
    float* Bnew;                        // B_i f32 plane
    const float2* rn;                   // r_{i+1} f32, read as pairs
    const float2* ss2;                  // interleaved f32 src/seg
    float* out;
};

// 2 px/thread, one image row per block.
// B_i = r_{i+1}@px + bilerp(B_{i-1}, def_i); phi0 warped through def_i;
// out = bilerp(src, phi0) + B_i * MU2L * bilerp(seg, phi0).
template <int FIRST, int WR>
__global__ __launch_bounds__(256) void k_step(StepArgs A) {
    const int tid = threadIdx.x;
    int phys = blockIdx.x;
    // XCD-contiguous swizzle: phys%8 -> XCD; give each XCD a contiguous 1/8.
    int logical = ((phys & 7) * (G2_ / 8)) + (phys >> 3);
    int tid2 = logical * 256 + tid;           // pixel-pair index
    int p0 = tid2 * 2;
    int x = p0 & (W_ - 1);                    // even; pair = x, x+1 (same row)
    int y = (p0 >> 9) & (H_ - 1);
    int b = p0 >> 18;
    size_t base = (size_t)b * HW_;

    float2 rv = A.rn[tid2];                   // r_{i+1} at the pixel pair
    uint2 dv = A.def[tid2];
    float2 d0 = upk(dv.x), d1 = upk(dv.y);
    Bil bw0 = mk_full((float)x - d0.x, (float)y - d0.y);
    Bil bw1 = mk_full((float)(x + 1) - d1.x, (float)y - d1.y);

    float B0 = rv.x, B1 = rv.y;
    BilL q0 = bw0.l, q1 = bw1.l;              // FIRST: phi0 == def_0

    if (!FIRST) {
        int a00, a01, a10, a11, e00, e01, e10, e11;
        gidx(bw0.l, a00, a01, a10, a11);
        gidx(bw1.l, e00, e01, e10, e11);
        const unsigned* pp = A.p0_old + base;
        unsigned s00 = pp[a00], s01 = pp[a01], s10 = pp[a10], s11 = pp[a11];
        unsigned t00 = pp[e00], t01 = pp[e01], t10 = pp[e10], t11 = pp[e11];
        const float* Bp = A.Bold + base;
        float f00 = Bp[a00], f01 = Bp[a01], f10 = Bp[a10], f11 = Bp[a11];
        float g00 = Bp[e00], g01 = Bp[e01], g10 = Bp[e10], g11 = Bp[e11];
        float wx0, wy0, wx1, wy1;
        warp_from(s00, s01, s10, s11, bw0, wx0, wy0);
        warp_from(t00, t01, t10, t11, bw1, wx1, wy1);
        B0 += f00 * bw0.l.w00 + f01 * bw0.l.w01 + f10 * bw0.l.w10 + f11 * bw0.l.w11;
        B1 += g00 * bw1.l.w00 + g01 * bw1.l.w01 + g10 * bw1.l.w10 + g11 * bw1.l.w11;
        if (WR) {
            reinterpret_cast<uint2*>(A.p0_new)[tid2] =
                make_uint2(pkh((float)x - wx0, (float)y - wy0),
                           pkh((float)(x + 1) - wx1, (float)y - wy1));
            reinterpret_cast<float2*>(A.Bnew)[tid2] = make_float2(B0, B1);
        }
        q0 = mk_lite(wx0, wy0);
        q1 = mk_lite(wx1, wy1);
    }

    const float2* ssp = A.ss2 + base;
    int i00, i01, i10, i11;
    gidx(q0, i00, i01, i10, i11);
    float2 c00 = ssp[i00], c01 = ssp[i01], c10 = ssp[i10], c11 = ssp[i11];
    float si0 = c00.x * q0.w00 + c01.x * q0.w01 + c10.x * q0.w10 + c11.x * q0.w11;
    float ss0 = c00.y * q0.w00 + c01.y * q0.w01 + c10.y * q0.w10 + c11.y * q0.w11;
    gidx(q1, i00, i01, i10, i11);
    float2 e00v = ssp[i00], e01v = ssp[i01], e10v = ssp[i10], e11v = ssp[i11];
    float si1 = e00v.x * q1.w00 + e01v.x * q1.w01 + e10v.x * q1.w10 + e11v.x * q1.w11;
    float ss1 = e00v.y * q1.w00 + e01v.y * q1.w01 + e10v.y * q1.w10 + e11v.y * q1.w11;

    float2 o = make_float2(si0 + B0 * MU2L * ss0, si1 + B1 * MU2L * ss1);
    reinterpret_cast<float2*>(A.out)[tid2] = o;
}

// diagnostic fallback (normalized error 0.96 signature == ws too small)
__global__ __launch_bounds__(256) void k_copy(const float* __restrict__ a,
                                              float* __restrict__ o) {
    int idx = blockIdx.x * 256 + threadIdx.x;
    o[idx] = a[idx];
}

} // namespace

extern "C" void kernel_launch(void* const* d_in, const int* in_sizes, int n_in,
                              void* d_out, int out_size, void* d_ws, size_t ws_size,
                              hipStream_t stream) {
    const float* source = (const float*)d_in[0];
    const float* z0     = (const float*)d_in[1];
    const float* seg    = (const float*)d_in[2];
    float* out = (float*)d_out;

    const size_t UNIT = (size_t)N_ * 4;          // 16 MiB
    dim3 blk(256), g1(N_ / 256), g2(G2_), gA(16, 32, 16);

    if (ws_size < 10 * UNIT) {
        hipLaunchKernelGGL(k_copy, g1, blk, 0, stream, source, out);
        return;
    }

    char* basep = (char*)d_ws;
    float2*   ss2     = (float2*)basep;                       // u0,u1
    unsigned* defb[2] = {(unsigned*)(basep + 2 * UNIT),       // u2 (even i)
                         (unsigned*)(basep + 3 * UNIT)};      // u3 (odd i)
    unsigned* phb[2]  = {(unsigned*)(basep + 4 * UNIT),       // u4
                         (unsigned*)(basep + 5 * UNIT)};      // u5
    float*    Bb[2]   = {(float*)(basep + 6 * UNIT),          // u6
                         (float*)(basep + 7 * UNIT)};         // u7
    float*    rnb[2]  = {(float*)(basep + 8 * UNIT),          // u8
                         (float*)(basep + 9 * UNIT)};         // u9

    // ---- step 0 ----
    hipLaunchKernelGGL(k_pack2, g1, blk, 0, stream, source, seg, ss2);
    hipLaunchKernelGGL(k_A, gA, blk, 0, stream, source, z0, rnb[0],
                       (__half2*)defb[0]);
    {
        StepArgs A{};
        A.def = (const uint2*)defb[0];
        A.rn = (const float2*)rnb[0];
        A.ss2 = ss2; A.out = out;
        hipLaunchKernelGGL((k_step<1, 0>), g2, blk, 0, stream, A);
        // aliases for step 1: phi0^{(0)} = defb[0], B_0 = rnb[0]
    }

    // ---- steps 1..9 ----
    for (int i = 1; i < L_; i++) {
        float* rn_r = rnb[(i - 1) & 1];          // r_i   (read by k_A)
        float* rn_w = rnb[i & 1];                // r_{i+1}
        hipLaunchKernelGGL(k_A, gA, blk, 0, stream, (const float*)out, rn_r,
                           rn_w, (__half2*)defb[i & 1]);
        StepArgs A{};
        A.def = (const uint2*)defb[i & 1];
        A.p0_old = (i == 1) ? defb[0] : phb[(i & 1) ? 1 : 0];
        A.p0_new = phb[(i & 1) ? 0 : 1];
        A.Bold = (i == 1) ? rnb[0] : Bb[(i & 1) ? 1 : 0];
        A.Bnew = Bb[(i & 1) ? 0 : 1];
        A.rn = (const float2*)rn_w;
        A.ss2 = ss2; A.out = out;
        if (i < L_ - 1)
            hipLaunchKernelGGL((k_step<0, 1>), g2, blk, 0, stream, A);
        else
            hipLaunchKernelGGL((k_step<0, 0>), g2, blk, 0, stream, A);
    }
    (void)in_sizes; (void)n_in; (void)out_size;
}

// Round 6
// 839.904 us; speedup vs baseline: 2.3617x; 1.0737x over previous
//
#include <hip/hip_runtime.h>
#include <hip/hip_fp16.h>
#include <hip/hip_bf16.h>

// shooting_model: B=16, H=W=512, L=10, MU=0.05, KS=7, SIGMA=2
// R15: algebraic restructure -- one f32 accumulated-residual plane B and
// phi0 replace the 9-plane phi/residual history (error enters at MU^2/L).
// R16: k_A v-blur HOISTED. Previously each thread re-evaluated the 7-tap
// vertical blur 14x per px inside V() (196 FMA + 196 LDS reads/thread).
// Now one cooperative v-blur pass -> sTV[2][18][34] (aliases dead sS
// storage; LDS total unchanged 23KB), then the div stencil reads it.
// Bit-identical numerics (same FMA chains, computed once).

namespace {
constexpr int W_ = 512, H_ = 512, L_ = 10;
constexpr int HW_ = W_ * H_;          // 1<<18
constexpr int N_  = 16 * HW_;         // 4194304
constexpr int G2_ = N_ / 512;         // 8192 blocks (512 px per block = 1 row)
constexpr float INVL = 0.1f;
constexpr float MU2L = 2.5e-4f;       // MU^2/L

__device__ __constant__ float GW[7] = {
    0.07015933f, 0.13107488f, 0.19071282f, 0.21610594f,
    0.19071282f, 0.13107488f, 0.07015933f};

struct BilL {                          // floor ints + weights
    int x0, y0;
    float w00, w01, w10, w11;
};
struct Bil {                           // + clamped float corner coords
    BilL l;
    float xc0, xc1, yc0, yc1;
};

__device__ __forceinline__ BilL mk_lite(float gx, float gy) {
    gx = fminf(fmaxf(gx, -1.0e9f), 1.0e9f);
    gy = fminf(fmaxf(gy, -1.0e9f), 1.0e9f);
    float x0f = floorf(gx), y0f = floorf(gy);
    float wx = gx - x0f, wy = gy - y0f;
    int x0 = (int)x0f, y0 = (int)y0f;
    float vx0 = ((unsigned)x0 < (unsigned)W_) ? 1.f : 0.f;
    float vx1 = ((unsigned)(x0 + 1) < (unsigned)W_) ? 1.f : 0.f;
    float vy0 = ((unsigned)y0 < (unsigned)H_) ? 1.f : 0.f;
    float vy1 = ((unsigned)(y0 + 1) < (unsigned)H_) ? 1.f : 0.f;
    BilL b;
    b.x0 = x0; b.y0 = y0;
    b.w00 = (1.f - wx) * (1.f - wy) * vx0 * vy0;
    b.w01 = wx * (1.f - wy) * vx1 * vy0;
    b.w10 = (1.f - wx) * wy * vx0 * vy1;
    b.w11 = wx * wy * vx1 * vy1;
    return b;
}

__device__ __forceinline__ Bil mk_full(float gx, float gy) {
    Bil b;
    b.l = mk_lite(gx, gy);
    int xc0 = min(max(b.l.x0, 0), W_ - 1), xc1 = min(max(b.l.x0 + 1, 0), W_ - 1);
    int yc0 = min(max(b.l.y0, 0), H_ - 1), yc1 = min(max(b.l.y0 + 1, 0), H_ - 1);
    b.xc0 = (float)xc0; b.xc1 = (float)xc1;
    b.yc0 = (float)yc0; b.yc1 = (float)yc1;
    return b;
}

__device__ __forceinline__ void gidx(const BilL& b, int& i00, int& i01,
                                     int& i10, int& i11) {
    int xc0 = min(max(b.x0, 0), W_ - 1), xc1 = min(max(b.x0 + 1, 0), W_ - 1);
    int yc0 = min(max(b.y0, 0), H_ - 1), yc1 = min(max(b.y0 + 1, 0), H_ - 1);
    i00 = yc0 * W_ + xc0; i01 = yc0 * W_ + xc1;
    i10 = yc1 * W_ + xc0; i11 = yc1 * W_ + xc1;
}

__device__ __forceinline__ float2 upk(unsigned u) {
    __half2 h; *reinterpret_cast<unsigned*>(&h) = u;
    return __half22float2(h);
}
__device__ __forceinline__ unsigned pkh(float a, float b) {
    __half2 h = __floats2half2_rn(a, b);
    return *reinterpret_cast<unsigned*>(&h);
}

// phi buffers store DISPLACEMENT (id - phi_abs) as half2, like def.
__device__ __forceinline__ void warp_from(unsigned v00, unsigned v01,
                                          unsigned v10, unsigned v11,
                                          const Bil& bw, float& wxo, float& wyo) {
    float2 s00 = upk(v00), s01 = upk(v01), s10 = upk(v10), s11 = upk(v11);
    wxo = bw.l.w00 * (bw.xc0 - s00.x) + bw.l.w01 * (bw.xc1 - s01.x)
        + bw.l.w10 * (bw.xc0 - s10.x) + bw.l.w11 * (bw.xc1 - s11.x);
    wyo = bw.l.w00 * (bw.yc0 - s00.y) + bw.l.w01 * (bw.yc0 - s01.y)
        + bw.l.w10 * (bw.yc1 - s10.y) + bw.l.w11 * (bw.yc1 - s11.y);
}

// pack src/seg f32 -> interleaved float2 (exact copy)
__global__ __launch_bounds__(256) void k_pack2(const float* __restrict__ src,
                                               const float* __restrict__ seg,
                                               float2* __restrict__ out) {
    int idx = blockIdx.x * 256 + threadIdx.x;
    out[idx] = make_float2(src[idx], seg[idx]);
}

// Fused dynamics: sobel(image)*(-r) -> separable 7x7 gaussian -> v;
// f = div(r*v)/L; rnext = r - f (f32); phi = v/L (half2 displacement).
__global__ __launch_bounds__(256) void k_A(const float* __restrict__ img,
                                           const float* __restrict__ rin,
                                           float* __restrict__ rnext_f,
                                           __half2* __restrict__ phi_new) {
    __shared__ float sI[26][43];
    __shared__ float sR[24][41];
    __shared__ float sS[2][24][41];     // sobel products; reused as sTV
    __shared__ float sTH[2][24][35];
    // v-blur result v(y0-1+r, x0-1+c), r in [0,18), c in [0,34); aliases sS
    float (*sTV)[18][35] = reinterpret_cast<float (*)[18][35]>(&sS[0][0][0]);
    const int t = threadIdx.x;
    const int x0 = blockIdx.x * 32, y0 = blockIdx.y * 16, b = blockIdx.z;
    const float* ip = img + (size_t)b * HW_;
    const float* rp = rin + (size_t)b * HW_;
    for (int u = t; u < 26 * 42; u += 256) {
        int r = u / 42, c = u % 42;
        int gy = min(max(y0 - 5 + r, 0), H_ - 1);
        int gx = min(max(x0 - 5 + c, 0), W_ - 1);
        sI[r][c] = ip[gy * W_ + gx];
    }
    for (int u = t; u < 24 * 40; u += 256) {
        int r = u / 40, c = u % 40;
        int gy = y0 - 4 + r, gx = x0 - 4 + c;
        sR[r][c] = ((unsigned)gy < (unsigned)H_ && (unsigned)gx < (unsigned)W_)
                 ? rp[gy * W_ + gx] : 0.f;
    }
    __syncthreads();
    for (int u = t; u < 24 * 40; u += 256) {   // s = -r * sobel(img)
        int r = u / 40, c = u % 40;
        float a00 = sI[r][c],     a01 = sI[r][c + 1],     a02 = sI[r][c + 2];
        float a10 = sI[r + 1][c],                          a12 = sI[r + 1][c + 2];
        float a20 = sI[r + 2][c], a21 = sI[r + 2][c + 1], a22 = sI[r + 2][c + 2];
        float gxv = ((a02 - a00) + 2.f * (a12 - a10) + (a22 - a20)) * 0.125f;
        float gyv = ((a20 - a00) + 2.f * (a21 - a01) + (a22 - a02)) * 0.125f;
        float rv = sR[r][c];
        sS[0][r][c] = -rv * gxv;
        sS[1][r][c] = -rv * gyv;
    }
    __syncthreads();
    for (int u = t; u < 24 * 34; u += 256) {   // th = h-blur(s)
        int r = u / 34, c = u % 34;
        float t0 = 0.f, t1 = 0.f;
#pragma unroll
        for (int k = 0; k < 7; k++) {
            t0 += GW[k] * sS[0][r][c + k];
            t1 += GW[k] * sS[1][r][c + k];
        }
        sTH[0][r][c] = t0; sTH[1][r][c] = t1;
    }
    __syncthreads();                           // sS dead; sTV may overwrite
    for (int u = t; u < 2 * 18 * 34; u += 256) {  // v = v-blur(th), hoisted
        int ch = u / (18 * 34), rem = u - ch * (18 * 34);
        int r = rem / 34, c = rem - r * 34;
        float s = 0.f;
#pragma unroll
        for (int k = 0; k < 7; k++) s += GW[k] * sTH[ch][r + k][c];
        sTV[ch][r][c] = s;
    }
    __syncthreads();
    const int tx = t & 15, ty = t >> 4;        // 2 px/thread in x
    const int y = y0 + ty;
    float rn2[2]; unsigned ph2[2];
#pragma unroll
    for (int px = 0; px < 2; px++) {
        const int lx = tx * 2 + px;
        const int x = x0 + lx;
        auto Vv = [&](int ch, int dy, int dx) -> float {
            return sTV[ch][ty + 1 + dy][lx + 1 + dx];
        };
        auto Wt = [&](int ch, int dy, int dx) -> float {
            int yy = y + dy, xx = x + dx;
            if ((unsigned)yy >= (unsigned)H_ || (unsigned)xx >= (unsigned)W_) return 0.f;
            return sR[ty + 4 + dy][lx + 4 + dx] * Vv(ch, dy, dx);
        };
        float f = (Wt(0, -1, 1) - Wt(0, -1, -1)) + 2.f * (Wt(0, 0, 1) - Wt(0, 0, -1))
                + (Wt(0, 1, 1) - Wt(0, 1, -1))
                + (Wt(1, 1, -1) - Wt(1, -1, -1)) + 2.f * (Wt(1, 1, 0) - Wt(1, -1, 0))
                + (Wt(1, 1, 1) - Wt(1, -1, 1));
        f *= 0.0125f;                          // (1/8 div-kernel) * (1/L)
        rn2[px] = sR[ty + 4][lx + 4] - f;
        ph2[px] = pkh(Vv(0, 0, 0) * INVL, Vv(1, 0, 0) * INVL);
    }
    int idx0 = b * HW_ + y * W_ + x0 + tx * 2; // even
    *reinterpret_cast<float2*>(rnext_f + idx0) = make_float2(rn2[0], rn2[1]);
    *reinterpret_cast<uint2*>(phi_new + idx0) = make_uint2(ph2[0], ph2[1]);
}

struct StepArgs {
    const uint2* def;                   // def_i displacement (half2/px)
    const unsigned* p0_old;             // phi0 displacement (half2/px)
    unsigned* p0_new;
    const float* Bold;                  // B_{i-1} f32 plane
    float* Bnew;                        // B_i f32 plane
    const float2* rn;                   // r_{i+1} f32, read as pairs
    const float2* ss2;                  // interleaved f32 src/seg
    float* out;
};

// 2 px/thread, one image row per block.
// B_i = r_{i+1}@px + bilerp(B_{i-1}, def_i); phi0 warped through def_i;
// out = bilerp(src, phi0) + B_i * MU2L * bilerp(seg, phi0).
template <int FIRST, int WR>
__global__ __launch_bounds__(256) void k_step(StepArgs A) {
    const int tid = threadIdx.x;
    int phys = blockIdx.x;
    // XCD-contiguous swizzle: phys%8 -> XCD; give each XCD a contiguous 1/8.
    int logical = ((phys & 7) * (G2_ / 8)) + (phys >> 3);
    int tid2 = logical * 256 + tid;           // pixel-pair index
    int p0 = tid2 * 2;
    int x = p0 & (W_ - 1);                    // even; pair = x, x+1 (same row)
    int y = (p0 >> 9) & (H_ - 1);
    int b = p0 >> 18;
    size_t base = (size_t)b * HW_;

    float2 rv = A.rn[tid2];                   // r_{i+1} at the pixel pair
    uint2 dv = A.def[tid2];
    float2 d0 = upk(dv.x), d1 = upk(dv.y);
    Bil bw0 = mk_full((float)x - d0.x, (float)y - d0.y);
    Bil bw1 = mk_full((float)(x + 1) - d1.x, (float)y - d1.y);

    float B0 = rv.x, B1 = rv.y;
    BilL q0 = bw0.l, q1 = bw1.l;              // FIRST: phi0 == def_0

    if (!FIRST) {
        int a00, a01, a10, a11, e00, e01, e10, e11;
        gidx(bw0.l, a00, a01, a10, a11);
        gidx(bw1.l, e00, e01, e10, e11);
        const unsigned* pp = A.p0_old + base;
        unsigned s00 = pp[a00], s01 = pp[a01], s10 = pp[a10], s11 = pp[a11];
        unsigned t00 = pp[e00], t01 = pp[e01], t10 = pp[e10], t11 = pp[e11];
        const float* Bp = A.Bold + base;
        float f00 = Bp[a00], f01 = Bp[a01], f10 = Bp[a10], f11 = Bp[a11];
        float g00 = Bp[e00], g01 = Bp[e01], g10 = Bp[e10], g11 = Bp[e11];
        float wx0, wy0, wx1, wy1;
        warp_from(s00, s01, s10, s11, bw0, wx0, wy0);
        warp_from(t00, t01, t10, t11, bw1, wx1, wy1);
        B0 += f00 * bw0.l.w00 + f01 * bw0.l.w01 + f10 * bw0.l.w10 + f11 * bw0.l.w11;
        B1 += g00 * bw1.l.w00 + g01 * bw1.l.w01 + g10 * bw1.l.w10 + g11 * bw1.l.w11;
        if (WR) {
            reinterpret_cast<uint2*>(A.p0_new)[tid2] =
                make_uint2(pkh((float)x - wx0, (float)y - wy0),
                           pkh((float)(x + 1) - wx1, (float)y - wy1));
            reinterpret_cast<float2*>(A.Bnew)[tid2] = make_float2(B0, B1);
        }
        q0 = mk_lite(wx0, wy0);
        q1 = mk_lite(wx1, wy1);
    }

    const float2* ssp = A.ss2 + base;
    int i00, i01, i10, i11;
    gidx(q0, i00, i01, i10, i11);
    float2 c00 = ssp[i00], c01 = ssp[i01], c10 = ssp[i10], c11 = ssp[i11];
    float si0 = c00.x * q0.w00 + c01.x * q0.w01 + c10.x * q0.w10 + c11.x * q0.w11;
    float ss0 = c00.y * q0.w00 + c01.y * q0.w01 + c10.y * q0.w10 + c11.y * q0.w11;
    gidx(q1, i00, i01, i10, i11);
    float2 e00v = ssp[i00], e01v = ssp[i01], e10v = ssp[i10], e11v = ssp[i11];
    float si1 = e00v.x * q1.w00 + e01v.x * q1.w01 + e10v.x * q1.w10 + e11v.x * q1.w11;
    float ss1 = e00v.y * q1.w00 + e01v.y * q1.w01 + e10v.y * q1.w10 + e11v.y * q1.w11;

    float2 o = make_float2(si0 + B0 * MU2L * ss0, si1 + B1 * MU2L * ss1);
    reinterpret_cast<float2*>(A.out)[tid2] = o;
}

// diagnostic fallback (normalized error 0.96 signature == ws too small)
__global__ __launch_bounds__(256) void k_copy(const float* __restrict__ a,
                                              float* __restrict__ o) {
    int idx = blockIdx.x * 256 + threadIdx.x;
    o[idx] = a[idx];
}

} // namespace

extern "C" void kernel_launch(void* const* d_in, const int* in_sizes, int n_in,
                              void* d_out, int out_size, void* d_ws, size_t ws_size,
                              hipStream_t stream) {
    const float* source = (const float*)d_in[0];
    const float* z0     = (const float*)d_in[1];
    const float* seg    = (const float*)d_in[2];
    float* out = (float*)d_out;

    const size_t UNIT = (size_t)N_ * 4;          // 16 MiB
    dim3 blk(256), g1(N_ / 256), g2(G2_), gA(16, 32, 16);

    if (ws_size < 10 * UNIT) {
        hipLaunchKernelGGL(k_copy, g1, blk, 0, stream, source, out);
        return;
    }

    char* basep = (char*)d_ws;
    float2*   ss2     = (float2*)basep;                       // u0,u1
    unsigned* defb[2] = {(unsigned*)(basep + 2 * UNIT),       // u2 (even i)
                         (unsigned*)(basep + 3 * UNIT)};      // u3 (odd i)
    unsigned* phb[2]  = {(unsigned*)(basep + 4 * UNIT),       // u4
                         (unsigned*)(basep + 5 * UNIT)};      // u5
    float*    Bb[2]   = {(float*)(basep + 6 * UNIT),          // u6
                         (float*)(basep + 7 * UNIT)};         // u7
    float*    rnb[2]  = {(float*)(basep + 8 * UNIT),          // u8
                         (float*)(basep + 9 * UNIT)};         // u9

    // ---- step 0 ----
    hipLaunchKernelGGL(k_pack2, g1, blk, 0, stream, source, seg, ss2);
    hipLaunchKernelGGL(k_A, gA, blk, 0, stream, source, z0, rnb[0],
                       (__half2*)defb[0]);
    {
        StepArgs A{};
        A.def = (const uint2*)defb[0];
        A.rn = (const float2*)rnb[0];
        A.ss2 = ss2; A.out = out;
        hipLaunchKernelGGL((k_step<1, 0>), g2, blk, 0, stream, A);
        // aliases for step 1: phi0^{(0)} = defb[0], B_0 = rnb[0]
    }

    // ---- steps 1..9 ----
    for (int i = 1; i < L_; i++) {
        float* rn_r = rnb[(i - 1) & 1];          // r_i   (read by k_A)
        float* rn_w = rnb[i & 1];                // r_{i+1}
        hipLaunchKernelGGL(k_A, gA, blk, 0, stream, (const float*)out, rn_r,
                           rn_w, (__half2*)defb[i & 1]);
        StepArgs A{};
        A.def = (const uint2*)defb[i & 1];
        A.p0_old = (i == 1) ? defb[0] : phb[(i & 1) ? 1 : 0];
        A.p0_new = phb[(i & 1) ? 0 : 1];
        A.Bold = (i == 1) ? rnb[0] : Bb[(i & 1) ? 1 : 0];
        A.Bnew = Bb[(i & 1) ? 0 : 1];
        A.rn = (const float2*)rn_w;
        A.ss2 = ss2; A.out = out;
        if (i < L_ - 1)
            hipLaunchKernelGGL((k_step<0, 1>), g2, blk, 0, stream, A);
        else
            hipLaunchKernelGGL((k_step<0, 0>), g2, blk, 0, stream, A);
    }
    (void)in_sizes; (void)n_in; (void)out_size;
}

// Round 7
// 703.550 us; speedup vs baseline: 2.8194x; 1.1938x over previous
//
#include <hip/hip_runtime.h>
#include <hip/hip_fp16.h>
#include <hip/hip_bf16.h>

// shooting_model: B=16, H=W=512, L=10, MU=0.05, KS=7, SIGMA=2
// R15: algebraic restructure -- one f32 accumulated-residual plane B and
// phi0 replace the 9-plane phi/residual history (error enters at MU^2/L).
// R16: v-blur hoisted into sTV (cooperative pass, aliases dead sS).
// R17: k_step FUSED into k_A. def is only ever consumed at the pixel
// itself = sTV[ty+1][lx+1] (in LDS), so the def plane never goes to
// memory (saves 16MB write + gather read + a launch per step). Image is
// double-buffered (d_out <-> ws unit) to break the read-halo/write race.
// def round-trips through the same pkh/upk half2 conversion in-register
// -> bit-identical numerics vs R16. Dispatches 21 -> 11.

namespace {
constexpr int W_ = 512, H_ = 512, L_ = 10;
constexpr int HW_ = W_ * H_;          // 1<<18
constexpr int N_  = 16 * HW_;         // 4194304
constexpr float INVL = 0.1f;
constexpr float MU2L = 2.5e-4f;       // MU^2/L

__device__ __constant__ float GW[7] = {
    0.07015933f, 0.13107488f, 0.19071282f, 0.21610594f,
    0.19071282f, 0.13107488f, 0.07015933f};

struct BilL {                          // floor ints + weights
    int x0, y0;
    float w00, w01, w10, w11;
};
struct Bil {                           // + clamped float corner coords
    BilL l;
    float xc0, xc1, yc0, yc1;
};

__device__ __forceinline__ BilL mk_lite(float gx, float gy) {
    gx = fminf(fmaxf(gx, -1.0e9f), 1.0e9f);
    gy = fminf(fmaxf(gy, -1.0e9f), 1.0e9f);
    float x0f = floorf(gx), y0f = floorf(gy);
    float wx = gx - x0f, wy = gy - y0f;
    int x0 = (int)x0f, y0 = (int)y0f;
    float vx0 = ((unsigned)x0 < (unsigned)W_) ? 1.f : 0.f;
    float vx1 = ((unsigned)(x0 + 1) < (unsigned)W_) ? 1.f : 0.f;
    float vy0 = ((unsigned)y0 < (unsigned)H_) ? 1.f : 0.f;
    float vy1 = ((unsigned)(y0 + 1) < (unsigned)H_) ? 1.f : 0.f;
    BilL b;
    b.x0 = x0; b.y0 = y0;
    b.w00 = (1.f - wx) * (1.f - wy) * vx0 * vy0;
    b.w01 = wx * (1.f - wy) * vx1 * vy0;
    b.w10 = (1.f - wx) * wy * vx0 * vy1;
    b.w11 = wx * wy * vx1 * vy1;
    return b;
}

__device__ __forceinline__ Bil mk_full(float gx, float gy) {
    Bil b;
    b.l = mk_lite(gx, gy);
    int xc0 = min(max(b.l.x0, 0), W_ - 1), xc1 = min(max(b.l.x0 + 1, 0), W_ - 1);
    int yc0 = min(max(b.l.y0, 0), H_ - 1), yc1 = min(max(b.l.y0 + 1, 0), H_ - 1);
    b.xc0 = (float)xc0; b.xc1 = (float)xc1;
    b.yc0 = (float)yc0; b.yc1 = (float)yc1;
    return b;
}

__device__ __forceinline__ void gidx(const BilL& b, int& i00, int& i01,
                                     int& i10, int& i11) {
    int xc0 = min(max(b.x0, 0), W_ - 1), xc1 = min(max(b.x0 + 1, 0), W_ - 1);
    int yc0 = min(max(b.y0, 0), H_ - 1), yc1 = min(max(b.y0 + 1, 0), H_ - 1);
    i00 = yc0 * W_ + xc0; i01 = yc0 * W_ + xc1;
    i10 = yc1 * W_ + xc0; i11 = yc1 * W_ + xc1;
}

__device__ __forceinline__ float2 upk(unsigned u) {
    __half2 h; *reinterpret_cast<unsigned*>(&h) = u;
    return __half22float2(h);
}
__device__ __forceinline__ unsigned pkh(float a, float b) {
    __half2 h = __floats2half2_rn(a, b);
    return *reinterpret_cast<unsigned*>(&h);
}

// phi buffers store DISPLACEMENT (id - phi_abs) as half2, like def.
__device__ __forceinline__ void warp_from(unsigned v00, unsigned v01,
                                          unsigned v10, unsigned v11,
                                          const Bil& bw, float& wxo, float& wyo) {
    float2 s00 = upk(v00), s01 = upk(v01), s10 = upk(v10), s11 = upk(v11);
    wxo = bw.l.w00 * (bw.xc0 - s00.x) + bw.l.w01 * (bw.xc1 - s01.x)
        + bw.l.w10 * (bw.xc0 - s10.x) + bw.l.w11 * (bw.xc1 - s11.x);
    wyo = bw.l.w00 * (bw.yc0 - s00.y) + bw.l.w01 * (bw.yc0 - s01.y)
        + bw.l.w10 * (bw.yc1 - s10.y) + bw.l.w11 * (bw.yc1 - s11.y);
}

// pack src/seg f32 -> interleaved float2 (exact copy)
__global__ __launch_bounds__(256) void k_pack2(const float* __restrict__ src,
                                               const float* __restrict__ seg,
                                               float2* __restrict__ out) {
    int idx = blockIdx.x * 256 + threadIdx.x;
    out[idx] = make_float2(src[idx], seg[idx]);
}

// Fused step: dynamics (sobel -> separable blur -> v; rnext = r - div/L)
// + warp/B-update/output, all in one kernel. def = v/L stays in LDS.
// FIRST: i==0 (phi0 == def, B = r_1). WR: write p0_new/Bnew (i<9).
template <int FIRST, int WR>
__global__ __launch_bounds__(256) void k_F(const float* __restrict__ img,
                                           const float* __restrict__ rin,
                                           float* __restrict__ rnext_f,
                                           const unsigned* __restrict__ p0_old,
                                           unsigned* __restrict__ p0_new,
                                           const float* __restrict__ Bold,
                                           float* __restrict__ Bnew,
                                           const float2* __restrict__ ss2,
                                           float* __restrict__ outp) {
    __shared__ float sI[26][43];
    __shared__ float sR[24][41];
    __shared__ float sS[2][24][41];     // sobel products; reused as sTV
    __shared__ float sTH[2][24][35];
    // v-blur result v(y0-1+r, x0-1+c), r in [0,18), c in [0,34); aliases sS
    float (*sTV)[18][35] = reinterpret_cast<float (*)[18][35]>(&sS[0][0][0]);
    const int t = threadIdx.x;
    const int x0 = blockIdx.x * 32, y0 = blockIdx.y * 16, b = blockIdx.z;
    const size_t base = (size_t)b * HW_;
    const float* ip = img + base;
    const float* rp = rin + base;
    for (int u = t; u < 26 * 42; u += 256) {
        int r = u / 42, c = u % 42;
        int gy = min(max(y0 - 5 + r, 0), H_ - 1);
        int gx = min(max(x0 - 5 + c, 0), W_ - 1);
        sI[r][c] = ip[gy * W_ + gx];
    }
    for (int u = t; u < 24 * 40; u += 256) {
        int r = u / 40, c = u % 40;
        int gy = y0 - 4 + r, gx = x0 - 4 + c;
        sR[r][c] = ((unsigned)gy < (unsigned)H_ && (unsigned)gx < (unsigned)W_)
                 ? rp[gy * W_ + gx] : 0.f;
    }
    __syncthreads();
    for (int u = t; u < 24 * 40; u += 256) {   // s = -r * sobel(img)
        int r = u / 40, c = u % 40;
        float a00 = sI[r][c],     a01 = sI[r][c + 1],     a02 = sI[r][c + 2];
        float a10 = sI[r + 1][c],                          a12 = sI[r + 1][c + 2];
        float a20 = sI[r + 2][c], a21 = sI[r + 2][c + 1], a22 = sI[r + 2][c + 2];
        float gxv = ((a02 - a00) + 2.f * (a12 - a10) + (a22 - a20)) * 0.125f;
        float gyv = ((a20 - a00) + 2.f * (a21 - a01) + (a22 - a02)) * 0.125f;
        float rv = sR[r][c];
        sS[0][r][c] = -rv * gxv;
        sS[1][r][c] = -rv * gyv;
    }
    __syncthreads();
    for (int u = t; u < 24 * 34; u += 256) {   // th = h-blur(s)
        int r = u / 34, c = u % 34;
        float t0 = 0.f, t1 = 0.f;
#pragma unroll
        for (int k = 0; k < 7; k++) {
            t0 += GW[k] * sS[0][r][c + k];
            t1 += GW[k] * sS[1][r][c + k];
        }
        sTH[0][r][c] = t0; sTH[1][r][c] = t1;
    }
    __syncthreads();                           // sS dead; sTV may overwrite
    for (int u = t; u < 2 * 18 * 34; u += 256) {  // v = v-blur(th), hoisted
        int ch = u / (18 * 34), rem = u - ch * (18 * 34);
        int r = rem / 34, c = rem - r * 34;
        float s = 0.f;
#pragma unroll
        for (int k = 0; k < 7; k++) s += GW[k] * sTH[ch][r + k][c];
        sTV[ch][r][c] = s;
    }
    __syncthreads();
    const int tx = t & 15, ty = t >> 4;        // 2 px/thread in x
    const int y = y0 + ty;
    float rn2[2]; unsigned ph2[2];
#pragma unroll
    for (int px = 0; px < 2; px++) {
        const int lx = tx * 2 + px;
        const int x = x0 + lx;
        auto Vv = [&](int ch, int dy, int dx) -> float {
            return sTV[ch][ty + 1 + dy][lx + 1 + dx];
        };
        auto Wt = [&](int ch, int dy, int dx) -> float {
            int yy = y + dy, xx = x + dx;
            if ((unsigned)yy >= (unsigned)H_ || (unsigned)xx >= (unsigned)W_) return 0.f;
            return sR[ty + 4 + dy][lx + 4 + dx] * Vv(ch, dy, dx);
        };
        float f = (Wt(0, -1, 1) - Wt(0, -1, -1)) + 2.f * (Wt(0, 0, 1) - Wt(0, 0, -1))
                + (Wt(0, 1, 1) - Wt(0, 1, -1))
                + (Wt(1, 1, -1) - Wt(1, -1, -1)) + 2.f * (Wt(1, 1, 0) - Wt(1, -1, 0))
                + (Wt(1, 1, 1) - Wt(1, -1, 1));
        f *= 0.0125f;                          // (1/8 div-kernel) * (1/L)
        rn2[px] = sR[ty + 4][lx + 4] - f;
        ph2[px] = pkh(Vv(0, 0, 0) * INVL, Vv(1, 0, 0) * INVL);
    }
    const int idx0 = b * HW_ + y * W_ + x0 + tx * 2; // even
    *reinterpret_cast<float2*>(rnext_f + idx0) = make_float2(rn2[0], rn2[1]);

    // ---- fused step tail: warp phi0 / update B / assemble output ----
    const float2* ssp = ss2 + base;
    float Bv[2], ov[2]; unsigned p0w[2];
#pragma unroll
    for (int px = 0; px < 2; px++) {
        const int x = x0 + tx * 2 + px;
        float2 d = upk(ph2[px]);               // same half2 round-trip as R16
        Bil bw = mk_full((float)x - d.x, (float)y - d.y);
        float Bx = rn2[px];
        BilL q = bw.l;
        if (!FIRST) {
            int i00, i01, i10, i11; gidx(bw.l, i00, i01, i10, i11);
            const unsigned* pp = p0_old + base;
            unsigned s00 = pp[i00], s01 = pp[i01], s10 = pp[i10], s11 = pp[i11];
            const float* Bp = Bold + base;
            float f00 = Bp[i00], f01 = Bp[i01], f10 = Bp[i10], f11 = Bp[i11];
            float wx, wy;
            warp_from(s00, s01, s10, s11, bw, wx, wy);
            Bx += f00 * bw.l.w00 + f01 * bw.l.w01 + f10 * bw.l.w10 + f11 * bw.l.w11;
            if (WR) p0w[px] = pkh((float)x - wx, (float)y - wy);
            q = mk_lite(wx, wy);
        } else {
            if (WR) p0w[px] = ph2[px];         // phi0^{(0)} = def_0
        }
        int i00, i01, i10, i11; gidx(q, i00, i01, i10, i11);
        float2 c00 = ssp[i00], c01 = ssp[i01], c10 = ssp[i10], c11 = ssp[i11];
        float si = c00.x * q.w00 + c01.x * q.w01 + c10.x * q.w10 + c11.x * q.w11;
        float sg = c00.y * q.w00 + c01.y * q.w01 + c10.y * q.w10 + c11.y * q.w11;
        Bv[px] = Bx;
        ov[px] = si + Bx * MU2L * sg;
    }
    if (WR) {
        *reinterpret_cast<uint2*>(p0_new + idx0) = make_uint2(p0w[0], p0w[1]);
        *reinterpret_cast<float2*>(Bnew + idx0) = make_float2(Bv[0], Bv[1]);
    }
    *reinterpret_cast<float2*>(outp + idx0) = make_float2(ov[0], ov[1]);
}

// diagnostic fallback (normalized error 0.96 signature == ws too small)
__global__ __launch_bounds__(256) void k_copy(const float* __restrict__ a,
                                              float* __restrict__ o) {
    int idx = blockIdx.x * 256 + threadIdx.x;
    o[idx] = a[idx];
}

} // namespace

extern "C" void kernel_launch(void* const* d_in, const int* in_sizes, int n_in,
                              void* d_out, int out_size, void* d_ws, size_t ws_size,
                              hipStream_t stream) {
    const float* source = (const float*)d_in[0];
    const float* z0     = (const float*)d_in[1];
    const float* seg    = (const float*)d_in[2];
    float* out = (float*)d_out;

    const size_t UNIT = (size_t)N_ * 4;          // 16 MiB
    dim3 blk(256), g1(N_ / 256), gA(16, 32, 16);

    if (ws_size < 10 * UNIT) {
        hipLaunchKernelGGL(k_copy, g1, blk, 0, stream, source, out);
        return;
    }

    char* basep = (char*)d_ws;
    float2*   ss2    = (float2*)basep;                        // u0,u1
    float*    imgA   = (float*)(basep + 2 * UNIT);            // u2 (even i)
    unsigned* phb[2] = {(unsigned*)(basep + 4 * UNIT),        // u4
                        (unsigned*)(basep + 5 * UNIT)};       // u5
    float*    Bb[2]  = {(float*)(basep + 6 * UNIT),           // u6
                        (float*)(basep + 7 * UNIT)};          // u7
    float*    rnb[2] = {(float*)(basep + 8 * UNIT),           // u8
                        (float*)(basep + 9 * UNIT)};          // u9

    hipLaunchKernelGGL(k_pack2, g1, blk, 0, stream, source, seg, ss2);

    // F0: img=source, rin=z0 -> writes rnb[0], phb[0], Bb[0], imgA
    hipLaunchKernelGGL((k_F<1, 1>), gA, blk, 0, stream,
                       source, z0, rnb[0], (const unsigned*)nullptr, phb[0],
                       (const float*)nullptr, Bb[0], (const float2*)ss2, imgA);

    // F1..F9: odd i -> writes d_out; even i -> writes imgA. F9 -> d_out.
    for (int i = 1; i < L_; i++) {
        const float* img = (i & 1) ? imgA : out;   // written by F_{i-1}
        float* outp      = (i & 1) ? out : imgA;
        const float* rin = rnb[(i - 1) & 1];
        float* rn_w      = rnb[i & 1];
        const unsigned* p0o = phb[(i - 1) & 1];
        unsigned* p0n       = phb[i & 1];
        const float* Bo  = Bb[(i - 1) & 1];
        float* Bn        = Bb[i & 1];
        if (i < L_ - 1)
            hipLaunchKernelGGL((k_F<0, 1>), gA, blk, 0, stream,
                               img, rin, rn_w, p0o, p0n, Bo, Bn,
                               (const float2*)ss2, outp);
        else
            hipLaunchKernelGGL((k_F<0, 0>), gA, blk, 0, stream,
                               img, rin, rn_w, p0o, p0n, Bo, Bn,
                               (const float2*)ss2, outp);
    }
    (void)in_sizes; (void)n_in; (void)out_size;
}

// Round 8
// 686.329 us; speedup vs baseline: 2.8901x; 1.0251x over previous
//
#include <hip/hip_runtime.h>
#include <hip/hip_fp16.h>
#include <hip/hip_bf16.h>

// shooting_model: B=16, H=W=512, L=10, MU=0.05, KS=7, SIGMA=2
// R15: algebraic restructure -- one f32 accumulated-residual plane B and
// phi0 replace the 9-plane phi/residual history (error enters at MU^2/L).
// R16: v-blur hoisted into sTV (cooperative pass).
// R17: step fused into dynamics kernel; def never touches memory.
// R18: CHANNEL-PACKED blurs. s/th/tv stored as float2 (x,y channel pair)
// in LDS; blur FMAs via __builtin_elementwise_fma on float2 ext-vectors
// (lowers to v_pk_fma_f32 on gfx950 -> half the VALU issue), LDS traffic
// in blur passes via ds_read_b64/ds_write_b64 (half the issue slots).
// Per-channel FMA chain order unchanged -> bit-identical numerics.

namespace {
constexpr int W_ = 512, H_ = 512, L_ = 10;
constexpr int HW_ = W_ * H_;          // 1<<18
constexpr int N_  = 16 * HW_;         // 4194304
constexpr float INVL = 0.1f;
constexpr float MU2L = 2.5e-4f;       // MU^2/L

typedef float f2 __attribute__((ext_vector_type(2)));

__device__ __constant__ float GW[7] = {
    0.07015933f, 0.13107488f, 0.19071282f, 0.21610594f,
    0.19071282f, 0.13107488f, 0.07015933f};
__device__ __constant__ f2 GW2[7] = {
    {0.07015933f, 0.07015933f}, {0.13107488f, 0.13107488f},
    {0.19071282f, 0.19071282f}, {0.21610594f, 0.21610594f},
    {0.19071282f, 0.19071282f}, {0.13107488f, 0.13107488f},
    {0.07015933f, 0.07015933f}};

struct BilL {                          // floor ints + weights
    int x0, y0;
    float w00, w01, w10, w11;
};
struct Bil {                           // + clamped float corner coords
    BilL l;
    float xc0, xc1, yc0, yc1;
};

__device__ __forceinline__ BilL mk_lite(float gx, float gy) {
    gx = fminf(fmaxf(gx, -1.0e9f), 1.0e9f);
    gy = fminf(fmaxf(gy, -1.0e9f), 1.0e9f);
    float x0f = floorf(gx), y0f = floorf(gy);
    float wx = gx - x0f, wy = gy - y0f;
    int x0 = (int)x0f, y0 = (int)y0f;
    float vx0 = ((unsigned)x0 < (unsigned)W_) ? 1.f : 0.f;
    float vx1 = ((unsigned)(x0 + 1) < (unsigned)W_) ? 1.f : 0.f;
    float vy0 = ((unsigned)y0 < (unsigned)H_) ? 1.f : 0.f;
    float vy1 = ((unsigned)(y0 + 1) < (unsigned)H_) ? 1.f : 0.f;
    BilL b;
    b.x0 = x0; b.y0 = y0;
    b.w00 = (1.f - wx) * (1.f - wy) * vx0 * vy0;
    b.w01 = wx * (1.f - wy) * vx1 * vy0;
    b.w10 = (1.f - wx) * wy * vx0 * vy1;
    b.w11 = wx * wy * vx1 * vy1;
    return b;
}

__device__ __forceinline__ Bil mk_full(float gx, float gy) {
    Bil b;
    b.l = mk_lite(gx, gy);
    int xc0 = min(max(b.l.x0, 0), W_ - 1), xc1 = min(max(b.l.x0 + 1, 0), W_ - 1);
    int yc0 = min(max(b.l.y0, 0), H_ - 1), yc1 = min(max(b.l.y0 + 1, 0), H_ - 1);
    b.xc0 = (float)xc0; b.xc1 = (float)xc1;
    b.yc0 = (float)yc0; b.yc1 = (float)yc1;
    return b;
}

__device__ __forceinline__ void gidx(const BilL& b, int& i00, int& i01,
                                     int& i10, int& i11) {
    int xc0 = min(max(b.x0, 0), W_ - 1), xc1 = min(max(b.x0 + 1, 0), W_ - 1);
    int yc0 = min(max(b.y0, 0), H_ - 1), yc1 = min(max(b.y0 + 1, 0), H_ - 1);
    i00 = yc0 * W_ + xc0; i01 = yc0 * W_ + xc1;
    i10 = yc1 * W_ + xc0; i11 = yc1 * W_ + xc1;
}

__device__ __forceinline__ float2 upk(unsigned u) {
    __half2 h; *reinterpret_cast<unsigned*>(&h) = u;
    return __half22float2(h);
}
__device__ __forceinline__ unsigned pkh(float a, float b) {
    __half2 h = __floats2half2_rn(a, b);
    return *reinterpret_cast<unsigned*>(&h);
}

// phi buffers store DISPLACEMENT (id - phi_abs) as half2, like def.
__device__ __forceinline__ void warp_from(unsigned v00, unsigned v01,
                                          unsigned v10, unsigned v11,
                                          const Bil& bw, float& wxo, float& wyo) {
    float2 s00 = upk(v00), s01 = upk(v01), s10 = upk(v10), s11 = upk(v11);
    wxo = bw.l.w00 * (bw.xc0 - s00.x) + bw.l.w01 * (bw.xc1 - s01.x)
        + bw.l.w10 * (bw.xc0 - s10.x) + bw.l.w11 * (bw.xc1 - s11.x);
    wyo = bw.l.w00 * (bw.yc0 - s00.y) + bw.l.w01 * (bw.yc0 - s01.y)
        + bw.l.w10 * (bw.yc1 - s10.y) + bw.l.w11 * (bw.yc1 - s11.y);
}

// pack src/seg f32 -> interleaved float2 (exact copy)
__global__ __launch_bounds__(256) void k_pack2(const float* __restrict__ src,
                                               const float* __restrict__ seg,
                                               float2* __restrict__ out) {
    int idx = blockIdx.x * 256 + threadIdx.x;
    out[idx] = make_float2(src[idx], seg[idx]);
}

// Fused step: dynamics (sobel -> separable blur -> v; rnext = r - div/L)
// + warp/B-update/output. def = v/L stays in LDS.
// FIRST: i==0 (phi0 == def, B = r_1). WR: write p0_new/Bnew (i<9).
template <int FIRST, int WR>
__global__ __launch_bounds__(256) void k_F(const float* __restrict__ img,
                                           const float* __restrict__ rin,
                                           float* __restrict__ rnext_f,
                                           const unsigned* __restrict__ p0_old,
                                           unsigned* __restrict__ p0_new,
                                           const float* __restrict__ Bold,
                                           float* __restrict__ Bnew,
                                           const float2* __restrict__ ss2,
                                           float* __restrict__ outp) {
    __shared__ float sI[26][43];
    __shared__ float sR[24][41];
    __shared__ f2 sS2[24][41];          // channel-packed sobel products
    __shared__ f2 sTH2[24][35];         // channel-packed h-blur
    // v-blur result, channel-packed; aliases sS2 (dead after h-blur)
    f2 (*sTV2)[35] = reinterpret_cast<f2 (*)[35]>(&sS2[0][0]);
    const int t = threadIdx.x;
    const int x0 = blockIdx.x * 32, y0 = blockIdx.y * 16, b = blockIdx.z;
    const size_t base = (size_t)b * HW_;
    const float* ip = img + base;
    const float* rp = rin + base;
    for (int u = t; u < 26 * 42; u += 256) {
        int r = u / 42, c = u % 42;
        int gy = min(max(y0 - 5 + r, 0), H_ - 1);
        int gx = min(max(x0 - 5 + c, 0), W_ - 1);
        sI[r][c] = ip[gy * W_ + gx];
    }
    for (int u = t; u < 24 * 40; u += 256) {
        int r = u / 40, c = u % 40;
        int gy = y0 - 4 + r, gx = x0 - 4 + c;
        sR[r][c] = ((unsigned)gy < (unsigned)H_ && (unsigned)gx < (unsigned)W_)
                 ? rp[gy * W_ + gx] : 0.f;
    }
    __syncthreads();
    for (int u = t; u < 24 * 40; u += 256) {   // s = -r * sobel(img), packed
        int r = u / 40, c = u % 40;
        float a00 = sI[r][c],     a01 = sI[r][c + 1],     a02 = sI[r][c + 2];
        float a10 = sI[r + 1][c],                          a12 = sI[r + 1][c + 2];
        float a20 = sI[r + 2][c], a21 = sI[r + 2][c + 1], a22 = sI[r + 2][c + 2];
        float gxv = ((a02 - a00) + 2.f * (a12 - a10) + (a22 - a20)) * 0.125f;
        float gyv = ((a20 - a00) + 2.f * (a21 - a01) + (a22 - a02)) * 0.125f;
        float rv = sR[r][c];
        f2 sv; sv.x = -rv * gxv; sv.y = -rv * gyv;
        sS2[r][c] = sv;
    }
    __syncthreads();
    for (int u = t; u < 24 * 34; u += 256) {   // th = h-blur(s), packed
        int r = u / 34, c = u % 34;
        f2 acc = {0.f, 0.f};
#pragma unroll
        for (int k = 0; k < 7; k++)
            acc = __builtin_elementwise_fma(GW2[k], sS2[r][c + k], acc);
        sTH2[r][c] = acc;
    }
    __syncthreads();                           // sS2 dead; sTV2 may overwrite
    for (int u = t; u < 18 * 34; u += 256) {   // v = v-blur(th), packed
        int r = u / 34, c = u - (u / 34) * 34;
        f2 acc = {0.f, 0.f};
#pragma unroll
        for (int k = 0; k < 7; k++)
            acc = __builtin_elementwise_fma(GW2[k], sTH2[r + k][c], acc);
        sTV2[r][c] = acc;
    }
    __syncthreads();
    const int tx = t & 15, ty = t >> 4;        // 2 px/thread in x
    const int y = y0 + ty;
    float rn2[2]; unsigned ph2[2];
#pragma unroll
    for (int px = 0; px < 2; px++) {
        const int lx = tx * 2 + px;
        const int x = x0 + lx;
        auto Vv = [&](int ch, int dy, int dx) -> float {
            f2 v = sTV2[ty + 1 + dy][lx + 1 + dx];
            return ch ? v.y : v.x;
        };
        auto Wt = [&](int ch, int dy, int dx) -> float {
            int yy = y + dy, xx = x + dx;
            if ((unsigned)yy >= (unsigned)H_ || (unsigned)xx >= (unsigned)W_) return 0.f;
            return sR[ty + 4 + dy][lx + 4 + dx] * Vv(ch, dy, dx);
        };
        float f = (Wt(0, -1, 1) - Wt(0, -1, -1)) + 2.f * (Wt(0, 0, 1) - Wt(0, 0, -1))
                + (Wt(0, 1, 1) - Wt(0, 1, -1))
                + (Wt(1, 1, -1) - Wt(1, -1, -1)) + 2.f * (Wt(1, 1, 0) - Wt(1, -1, 0))
                + (Wt(1, 1, 1) - Wt(1, -1, 1));
        f *= 0.0125f;                          // (1/8 div-kernel) * (1/L)
        rn2[px] = sR[ty + 4][lx + 4] - f;
        ph2[px] = pkh(Vv(0, 0, 0) * INVL, Vv(1, 0, 0) * INVL);
    }
    const int idx0 = b * HW_ + y * W_ + x0 + tx * 2; // even
    *reinterpret_cast<float2*>(rnext_f + idx0) = make_float2(rn2[0], rn2[1]);

    // ---- fused step tail: warp phi0 / update B / assemble output ----
    const float2* ssp = ss2 + base;
    float Bv[2], ov[2]; unsigned p0w[2];
#pragma unroll
    for (int px = 0; px < 2; px++) {
        const int x = x0 + tx * 2 + px;
        float2 d = upk(ph2[px]);               // same half2 round-trip as R16
        Bil bw = mk_full((float)x - d.x, (float)y - d.y);
        float Bx = rn2[px];
        BilL q = bw.l;
        if (!FIRST) {
            int i00, i01, i10, i11; gidx(bw.l, i00, i01, i10, i11);
            const unsigned* pp = p0_old + base;
            unsigned s00 = pp[i00], s01 = pp[i01], s10 = pp[i10], s11 = pp[i11];
            const float* Bp = Bold + base;
            float f00 = Bp[i00], f01 = Bp[i01], f10 = Bp[i10], f11 = Bp[i11];
            float wx, wy;
            warp_from(s00, s01, s10, s11, bw, wx, wy);
            Bx += f00 * bw.l.w00 + f01 * bw.l.w01 + f10 * bw.l.w10 + f11 * bw.l.w11;
            if (WR) p0w[px] = pkh((float)x - wx, (float)y - wy);
            q = mk_lite(wx, wy);
        } else {
            if (WR) p0w[px] = ph2[px];         // phi0^{(0)} = def_0
        }
        int i00, i01, i10, i11; gidx(q, i00, i01, i10, i11);
        float2 c00 = ssp[i00], c01 = ssp[i01], c10 = ssp[i10], c11 = ssp[i11];
        float si = c00.x * q.w00 + c01.x * q.w01 + c10.x * q.w10 + c11.x * q.w11;
        float sg = c00.y * q.w00 + c01.y * q.w01 + c10.y * q.w10 + c11.y * q.w11;
        Bv[px] = Bx;
        ov[px] = si + Bx * MU2L * sg;
    }
    if (WR) {
        *reinterpret_cast<uint2*>(p0_new + idx0) = make_uint2(p0w[0], p0w[1]);
        *reinterpret_cast<float2*>(Bnew + idx0) = make_float2(Bv[0], Bv[1]);
    }
    *reinterpret_cast<float2*>(outp + idx0) = make_float2(ov[0], ov[1]);
}

// diagnostic fallback (normalized error 0.96 signature == ws too small)
__global__ __launch_bounds__(256) void k_copy(const float* __restrict__ a,
                                              float* __restrict__ o) {
    int idx = blockIdx.x * 256 + threadIdx.x;
    o[idx] = a[idx];
}

} // namespace

extern "C" void kernel_launch(void* const* d_in, const int* in_sizes, int n_in,
                              void* d_out, int out_size, void* d_ws, size_t ws_size,
                              hipStream_t stream) {
    const float* source = (const float*)d_in[0];
    const float* z0     = (const float*)d_in[1];
    const float* seg    = (const float*)d_in[2];
    float* out = (float*)d_out;

    const size_t UNIT = (size_t)N_ * 4;          // 16 MiB
    dim3 blk(256), g1(N_ / 256), gA(16, 32, 16);

    if (ws_size < 10 * UNIT) {
        hipLaunchKernelGGL(k_copy, g1, blk, 0, stream, source, out);
        return;
    }

    char* basep = (char*)d_ws;
    float2*   ss2    = (float2*)basep;                        // u0,u1
    float*    imgA   = (float*)(basep + 2 * UNIT);            // u2 (even i)
    unsigned* phb[2] = {(unsigned*)(basep + 4 * UNIT),        // u4
                        (unsigned*)(basep + 5 * UNIT)};       // u5
    float*    Bb[2]  = {(float*)(basep + 6 * UNIT),           // u6
                        (float*)(basep + 7 * UNIT)};          // u7
    float*    rnb[2] = {(float*)(basep + 8 * UNIT),           // u8
                        (float*)(basep + 9 * UNIT)};          // u9

    hipLaunchKernelGGL(k_pack2, g1, blk, 0, stream, source, seg, ss2);

    // F0: img=source, rin=z0 -> writes rnb[0], phb[0], Bb[0], imgA
    hipLaunchKernelGGL((k_F<1, 1>), gA, blk, 0, stream,
                       source, z0, rnb[0], (const unsigned*)nullptr, phb[0],
                       (const float*)nullptr, Bb[0], (const float2*)ss2, imgA);

    // F1..F9: odd i -> writes d_out; even i -> writes imgA. F9 -> d_out.
    for (int i = 1; i < L_; i++) {
        const float* img = (i & 1) ? imgA : out;   // written by F_{i-1}
        float* outp      = (i & 1) ? out : imgA;
        const float* rin = rnb[(i - 1) & 1];
        float* rn_w      = rnb[i & 1];
        const unsigned* p0o = phb[(i - 1) & 1];
        unsigned* p0n       = phb[i & 1];
        const float* Bo  = Bb[(i - 1) & 1];
        float* Bn        = Bb[i & 1];
        if (i < L_ - 1)
            hipLaunchKernelGGL((k_F<0, 1>), gA, blk, 0, stream,
                               img, rin, rn_w, p0o, p0n, Bo, Bn,
                               (const float2*)ss2, outp);
        else
            hipLaunchKernelGGL((k_F<0, 0>), gA, blk, 0, stream,
                               img, rin, rn_w, p0o, p0n, Bo, Bn,
                               (const float2*)ss2, outp);
    }
    (void)in_sizes; (void)n_in; (void)out_size;
}

// Round 9
// 673.928 us; speedup vs baseline: 2.9433x; 1.0184x over previous
//
#include <hip/hip_runtime.h>
#include <hip/hip_fp16.h>
#include <hip/hip_bf16.h>

// shooting_model: B=16, H=W=512, L=10, MU=0.05, KS=7, SIGMA=2
// R15: algebraic restructure -- one f32 accumulated-residual plane B and
// phi0 replace the 9-plane phi/residual history (error enters at MU^2/L).
// R16: v-blur hoisted into sTV (cooperative pass).
// R17: step fused into dynamics kernel; def never touches memory.
// R18: channel-packed (f2) blurs -> v_pk_fma_f32, b64 LDS ops.
// R19: REGISTER-BLOCKED passes (2 elems/thread). Diagnosis: R18 cut VALU
// issue 25% (VALUBusy 71->57) with ~no dur change -> co-bound on LDS issue.
// Pairing elements shares overlapping LDS reads in registers: sobel 22->16,
// h-blur 16->10, v-blur 16->10 DS ops per 2 elems (-33% pass DS). Per-elem
// FMA chains textually identical -> bit-identical numerics.

namespace {
constexpr int W_ = 512, H_ = 512, L_ = 10;
constexpr int HW_ = W_ * H_;          // 1<<18
constexpr int N_  = 16 * HW_;         // 4194304
constexpr float INVL = 0.1f;
constexpr float MU2L = 2.5e-4f;       // MU^2/L

typedef float f2 __attribute__((ext_vector_type(2)));

__device__ __constant__ f2 GW2[7] = {
    {0.07015933f, 0.07015933f}, {0.13107488f, 0.13107488f},
    {0.19071282f, 0.19071282f}, {0.21610594f, 0.21610594f},
    {0.19071282f, 0.19071282f}, {0.13107488f, 0.13107488f},
    {0.07015933f, 0.07015933f}};

struct BilL {                          // floor ints + weights
    int x0, y0;
    float w00, w01, w10, w11;
};
struct Bil {                           // + clamped float corner coords
    BilL l;
    float xc0, xc1, yc0, yc1;
};

__device__ __forceinline__ BilL mk_lite(float gx, float gy) {
    gx = fminf(fmaxf(gx, -1.0e9f), 1.0e9f);
    gy = fminf(fmaxf(gy, -1.0e9f), 1.0e9f);
    float x0f = floorf(gx), y0f = floorf(gy);
    float wx = gx - x0f, wy = gy - y0f;
    int x0 = (int)x0f, y0 = (int)y0f;
    float vx0 = ((unsigned)x0 < (unsigned)W_) ? 1.f : 0.f;
    float vx1 = ((unsigned)(x0 + 1) < (unsigned)W_) ? 1.f : 0.f;
    float vy0 = ((unsigned)y0 < (unsigned)H_) ? 1.f : 0.f;
    float vy1 = ((unsigned)(y0 + 1) < (unsigned)H_) ? 1.f : 0.f;
    BilL b;
    b.x0 = x0; b.y0 = y0;
    b.w00 = (1.f - wx) * (1.f - wy) * vx0 * vy0;
    b.w01 = wx * (1.f - wy) * vx1 * vy0;
    b.w10 = (1.f - wx) * wy * vx0 * vy1;
    b.w11 = wx * wy * vx1 * vy1;
    return b;
}

__device__ __forceinline__ Bil mk_full(float gx, float gy) {
    Bil b;
    b.l = mk_lite(gx, gy);
    int xc0 = min(max(b.l.x0, 0), W_ - 1), xc1 = min(max(b.l.x0 + 1, 0), W_ - 1);
    int yc0 = min(max(b.l.y0, 0), H_ - 1), yc1 = min(max(b.l.y0 + 1, 0), H_ - 1);
    b.xc0 = (float)xc0; b.xc1 = (float)xc1;
    b.yc0 = (float)yc0; b.yc1 = (float)yc1;
    return b;
}

__device__ __forceinline__ void gidx(const BilL& b, int& i00, int& i01,
                                     int& i10, int& i11) {
    int xc0 = min(max(b.x0, 0), W_ - 1), xc1 = min(max(b.x0 + 1, 0), W_ - 1);
    int yc0 = min(max(b.y0, 0), H_ - 1), yc1 = min(max(b.y0 + 1, 0), H_ - 1);
    i00 = yc0 * W_ + xc0; i01 = yc0 * W_ + xc1;
    i10 = yc1 * W_ + xc0; i11 = yc1 * W_ + xc1;
}

__device__ __forceinline__ float2 upk(unsigned u) {
    __half2 h; *reinterpret_cast<unsigned*>(&h) = u;
    return __half22float2(h);
}
__device__ __forceinline__ unsigned pkh(float a, float b) {
    __half2 h = __floats2half2_rn(a, b);
    return *reinterpret_cast<unsigned*>(&h);
}

// phi buffers store DISPLACEMENT (id - phi_abs) as half2, like def.
__device__ __forceinline__ void warp_from(unsigned v00, unsigned v01,
                                          unsigned v10, unsigned v11,
                                          const Bil& bw, float& wxo, float& wyo) {
    float2 s00 = upk(v00), s01 = upk(v01), s10 = upk(v10), s11 = upk(v11);
    wxo = bw.l.w00 * (bw.xc0 - s00.x) + bw.l.w01 * (bw.xc1 - s01.x)
        + bw.l.w10 * (bw.xc0 - s10.x) + bw.l.w11 * (bw.xc1 - s11.x);
    wyo = bw.l.w00 * (bw.yc0 - s00.y) + bw.l.w01 * (bw.yc0 - s01.y)
        + bw.l.w10 * (bw.yc1 - s10.y) + bw.l.w11 * (bw.yc1 - s11.y);
}

// pack src/seg f32 -> interleaved float2 (exact copy)
__global__ __launch_bounds__(256) void k_pack2(const float* __restrict__ src,
                                               const float* __restrict__ seg,
                                               float2* __restrict__ out) {
    int idx = blockIdx.x * 256 + threadIdx.x;
    out[idx] = make_float2(src[idx], seg[idx]);
}

// Fused step: dynamics (sobel -> separable blur -> v; rnext = r - div/L)
// + warp/B-update/output. def = v/L stays in LDS.
// FIRST: i==0 (phi0 == def, B = r_1). WR: write p0_new/Bnew (i<9).
template <int FIRST, int WR>
__global__ __launch_bounds__(256) void k_F(const float* __restrict__ img,
                                           const float* __restrict__ rin,
                                           float* __restrict__ rnext_f,
                                           const unsigned* __restrict__ p0_old,
                                           unsigned* __restrict__ p0_new,
                                           const float* __restrict__ Bold,
                                           float* __restrict__ Bnew,
                                           const float2* __restrict__ ss2,
                                           float* __restrict__ outp) {
    __shared__ float sI[26][43];
    __shared__ float sR[24][41];
    __shared__ f2 sS2[24][41];          // channel-packed sobel products
    __shared__ f2 sTH2[24][35];         // channel-packed h-blur
    // v-blur result, channel-packed; aliases sS2 (dead after h-blur)
    f2 (*sTV2)[35] = reinterpret_cast<f2 (*)[35]>(&sS2[0][0]);
    const int t = threadIdx.x;
    const int x0 = blockIdx.x * 32, y0 = blockIdx.y * 16, b = blockIdx.z;
    const size_t base = (size_t)b * HW_;
    const float* ip = img + base;
    const float* rp = rin + base;
    for (int u = t; u < 26 * 42; u += 256) {
        int r = u / 42, c = u % 42;
        int gy = min(max(y0 - 5 + r, 0), H_ - 1);
        int gx = min(max(x0 - 5 + c, 0), W_ - 1);
        sI[r][c] = ip[gy * W_ + gx];
    }
    for (int u = t; u < 24 * 40; u += 256) {
        int r = u / 40, c = u % 40;
        int gy = y0 - 4 + r, gx = x0 - 4 + c;
        sR[r][c] = ((unsigned)gy < (unsigned)H_ && (unsigned)gx < (unsigned)W_)
                 ? rp[gy * W_ + gx] : 0.f;
    }
    __syncthreads();
    // s = -r * sobel(img), 2 elems/thread (shared sI reads)
    for (int u = t; u < 24 * 20; u += 256) {
        int r = u / 20, cp = u - (u / 20) * 20;
        int c = cp * 2;
        float a00 = sI[r][c],     a01 = sI[r][c + 1];
        float a02 = sI[r][c + 2], a03 = sI[r][c + 3];
        float a10 = sI[r + 1][c],     a11 = sI[r + 1][c + 1];
        float a12 = sI[r + 1][c + 2], a13 = sI[r + 1][c + 3];
        float a20 = sI[r + 2][c],     a21 = sI[r + 2][c + 1];
        float a22 = sI[r + 2][c + 2], a23 = sI[r + 2][c + 3];
        float rv0 = sR[r][c], rv1 = sR[r][c + 1];
        float gx0 = ((a02 - a00) + 2.f * (a12 - a10) + (a22 - a20)) * 0.125f;
        float gy0 = ((a20 - a00) + 2.f * (a21 - a01) + (a22 - a02)) * 0.125f;
        float gx1 = ((a03 - a01) + 2.f * (a13 - a11) + (a23 - a21)) * 0.125f;
        float gy1 = ((a21 - a01) + 2.f * (a22 - a02) + (a23 - a03)) * 0.125f;
        f2 s0; s0.x = -rv0 * gx0; s0.y = -rv0 * gy0;
        f2 s1; s1.x = -rv1 * gx1; s1.y = -rv1 * gy1;
        sS2[r][c] = s0; sS2[r][c + 1] = s1;
    }
    __syncthreads();
    // th = h-blur(s), 2 elems/thread (8 shared b64 reads)
    for (int u = t; u < 24 * 17; u += 256) {
        int r = u / 17, cp = u - (u / 17) * 17;
        int c = cp * 2;
        f2 w0 = sS2[r][c],     w1 = sS2[r][c + 1], w2 = sS2[r][c + 2];
        f2 w3 = sS2[r][c + 3], w4 = sS2[r][c + 4], w5 = sS2[r][c + 5];
        f2 w6 = sS2[r][c + 6], w7 = sS2[r][c + 7];
        f2 a0 = {0.f, 0.f}, a1 = {0.f, 0.f};
        a0 = __builtin_elementwise_fma(GW2[0], w0, a0);
        a1 = __builtin_elementwise_fma(GW2[0], w1, a1);
        a0 = __builtin_elementwise_fma(GW2[1], w1, a0);
        a1 = __builtin_elementwise_fma(GW2[1], w2, a1);
        a0 = __builtin_elementwise_fma(GW2[2], w2, a0);
        a1 = __builtin_elementwise_fma(GW2[2], w3, a1);
        a0 = __builtin_elementwise_fma(GW2[3], w3, a0);
        a1 = __builtin_elementwise_fma(GW2[3], w4, a1);
        a0 = __builtin_elementwise_fma(GW2[4], w4, a0);
        a1 = __builtin_elementwise_fma(GW2[4], w5, a1);
        a0 = __builtin_elementwise_fma(GW2[5], w5, a0);
        a1 = __builtin_elementwise_fma(GW2[5], w6, a1);
        a0 = __builtin_elementwise_fma(GW2[6], w6, a0);
        a1 = __builtin_elementwise_fma(GW2[6], w7, a1);
        sTH2[r][c] = a0; sTH2[r][c + 1] = a1;
    }
    __syncthreads();                           // sS2 dead; sTV2 may overwrite
    // v = v-blur(th), 2 vertically-adjacent elems/thread (8 shared reads)
    for (int u = t; u < 9 * 34; u += 256) {
        int rpair = u / 34, c = u - rpair * 34;
        int r = rpair * 2;
        f2 w0 = sTH2[r][c],     w1 = sTH2[r + 1][c], w2 = sTH2[r + 2][c];
        f2 w3 = sTH2[r + 3][c], w4 = sTH2[r + 4][c], w5 = sTH2[r + 5][c];
        f2 w6 = sTH2[r + 6][c], w7 = sTH2[r + 7][c];
        f2 a0 = {0.f, 0.f}, a1 = {0.f, 0.f};
        a0 = __builtin_elementwise_fma(GW2[0], w0, a0);
        a1 = __builtin_elementwise_fma(GW2[0], w1, a1);
        a0 = __builtin_elementwise_fma(GW2[1], w1, a0);
        a1 = __builtin_elementwise_fma(GW2[1], w2, a1);
        a0 = __builtin_elementwise_fma(GW2[2], w2, a0);
        a1 = __builtin_elementwise_fma(GW2[2], w3, a1);
        a0 = __builtin_elementwise_fma(GW2[3], w3, a0);
        a1 = __builtin_elementwise_fma(GW2[3], w4, a1);
        a0 = __builtin_elementwise_fma(GW2[4], w4, a0);
        a1 = __builtin_elementwise_fma(GW2[4], w5, a1);
        a0 = __builtin_elementwise_fma(GW2[5], w5, a0);
        a1 = __builtin_elementwise_fma(GW2[5], w6, a1);
        a0 = __builtin_elementwise_fma(GW2[6], w6, a0);
        a1 = __builtin_elementwise_fma(GW2[6], w7, a1);
        sTV2[r][c] = a0; sTV2[r + 1][c] = a1;
    }
    __syncthreads();
    const int tx = t & 15, ty = t >> 4;        // 2 px/thread in x
    const int y = y0 + ty;
    float rn2[2]; unsigned ph2[2];
#pragma unroll
    for (int px = 0; px < 2; px++) {
        const int lx = tx * 2 + px;
        const int x = x0 + lx;
        auto Vv = [&](int ch, int dy, int dx) -> float {
            f2 v = sTV2[ty + 1 + dy][lx + 1 + dx];
            return ch ? v.y : v.x;
        };
        auto Wt = [&](int ch, int dy, int dx) -> float {
            int yy = y + dy, xx = x + dx;
            if ((unsigned)yy >= (unsigned)H_ || (unsigned)xx >= (unsigned)W_) return 0.f;
            return sR[ty + 4 + dy][lx + 4 + dx] * Vv(ch, dy, dx);
        };
        float f = (Wt(0, -1, 1) - Wt(0, -1, -1)) + 2.f * (Wt(0, 0, 1) - Wt(0, 0, -1))
                + (Wt(0, 1, 1) - Wt(0, 1, -1))
                + (Wt(1, 1, -1) - Wt(1, -1, -1)) + 2.f * (Wt(1, 1, 0) - Wt(1, -1, 0))
                + (Wt(1, 1, 1) - Wt(1, -1, 1));
        f *= 0.0125f;                          // (1/8 div-kernel) * (1/L)
        rn2[px] = sR[ty + 4][lx + 4] - f;
        ph2[px] = pkh(Vv(0, 0, 0) * INVL, Vv(1, 0, 0) * INVL);
    }
    const int idx0 = b * HW_ + y * W_ + x0 + tx * 2; // even
    *reinterpret_cast<float2*>(rnext_f + idx0) = make_float2(rn2[0], rn2[1]);

    // ---- fused step tail: warp phi0 / update B / assemble output ----
    const float2* ssp = ss2 + base;
    float Bv[2], ov[2]; unsigned p0w[2];
#pragma unroll
    for (int px = 0; px < 2; px++) {
        const int x = x0 + tx * 2 + px;
        float2 d = upk(ph2[px]);               // same half2 round-trip as R16
        Bil bw = mk_full((float)x - d.x, (float)y - d.y);
        float Bx = rn2[px];
        BilL q = bw.l;
        if (!FIRST) {
            int i00, i01, i10, i11; gidx(bw.l, i00, i01, i10, i11);
            const unsigned* pp = p0_old + base;
            unsigned s00 = pp[i00], s01 = pp[i01], s10 = pp[i10], s11 = pp[i11];
            const float* Bp = Bold + base;
            float f00 = Bp[i00], f01 = Bp[i01], f10 = Bp[i10], f11 = Bp[i11];
            float wx, wy;
            warp_from(s00, s01, s10, s11, bw, wx, wy);
            Bx += f00 * bw.l.w00 + f01 * bw.l.w01 + f10 * bw.l.w10 + f11 * bw.l.w11;
            if (WR) p0w[px] = pkh((float)x - wx, (float)y - wy);
            q = mk_lite(wx, wy);
        } else {
            if (WR) p0w[px] = ph2[px];         // phi0^{(0)} = def_0
        }
        int i00, i01, i10, i11; gidx(q, i00, i01, i10, i11);
        float2 c00 = ssp[i00], c01 = ssp[i01], c10 = ssp[i10], c11 = ssp[i11];
        float si = c00.x * q.w00 + c01.x * q.w01 + c10.x * q.w10 + c11.x * q.w11;
        float sg = c00.y * q.w00 + c01.y * q.w01 + c10.y * q.w10 + c11.y * q.w11;
        Bv[px] = Bx;
        ov[px] = si + Bx * MU2L * sg;
    }
    if (WR) {
        *reinterpret_cast<uint2*>(p0_new + idx0) = make_uint2(p0w[0], p0w[1]);
        *reinterpret_cast<float2*>(Bnew + idx0) = make_float2(Bv[0], Bv[1]);
    }
    *reinterpret_cast<float2*>(outp + idx0) = make_float2(ov[0], ov[1]);
}

// diagnostic fallback (normalized error 0.96 signature == ws too small)
__global__ __launch_bounds__(256) void k_copy(const float* __restrict__ a,
                                              float* __restrict__ o) {
    int idx = blockIdx.x * 256 + threadIdx.x;
    o[idx] = a[idx];
}

} // namespace

extern "C" void kernel_launch(void* const* d_in, const int* in_sizes, int n_in,
                              void* d_out, int out_size, void* d_ws, size_t ws_size,
                              hipStream_t stream) {
    const float* source = (const float*)d_in[0];
    const float* z0     = (const float*)d_in[1];
    const float* seg    = (const float*)d_in[2];
    float* out = (float*)d_out;

    const size_t UNIT = (size_t)N_ * 4;          // 16 MiB
    dim3 blk(256), g1(N_ / 256), gA(16, 32, 16);

    if (ws_size < 10 * UNIT) {
        hipLaunchKernelGGL(k_copy, g1, blk, 0, stream, source, out);
        return;
    }

    char* basep = (char*)d_ws;
    float2*   ss2    = (float2*)basep;                        // u0,u1
    float*    imgA   = (float*)(basep + 2 * UNIT);            // u2 (even i)
    unsigned* phb[2] = {(unsigned*)(basep + 4 * UNIT),        // u4
                        (unsigned*)(basep + 5 * UNIT)};       // u5
    float*    Bb[2]  = {(float*)(basep + 6 * UNIT),           // u6
                        (float*)(basep + 7 * UNIT)};          // u7
    float*    rnb[2] = {(float*)(basep + 8 * UNIT),           // u8
                        (float*)(basep + 9 * UNIT)};          // u9

    hipLaunchKernelGGL(k_pack2, g1, blk, 0, stream, source, seg, ss2);

    // F0: img=source, rin=z0 -> writes rnb[0], phb[0], Bb[0], imgA
    hipLaunchKernelGGL((k_F<1, 1>), gA, blk, 0, stream,
                       source, z0, rnb[0], (const unsigned*)nullptr, phb[0],
                       (const float*)nullptr, Bb[0], (const float2*)ss2, imgA);

    // F1..F9: odd i -> writes d_out; even i -> writes imgA. F9 -> d_out.
    for (int i = 1; i < L_; i++) {
        const float* img = (i & 1) ? imgA : out;   // written by F_{i-1}
        float* outp      = (i & 1) ? out : imgA;
        const float* rin = rnb[(i - 1) & 1];
        float* rn_w      = rnb[i & 1];
        const unsigned* p0o = phb[(i - 1) & 1];
        unsigned* p0n       = phb[i & 1];
        const float* Bo  = Bb[(i - 1) & 1];
        float* Bn        = Bb[i & 1];
        if (i < L_ - 1)
            hipLaunchKernelGGL((k_F<0, 1>), gA, blk, 0, stream,
                               img, rin, rn_w, p0o, p0n, Bo, Bn,
                               (const float2*)ss2, outp);
        else
            hipLaunchKernelGGL((k_F<0, 0>), gA, blk, 0, stream,
                               img, rin, rn_w, p0o, p0n, Bo, Bn,
                               (const float2*)ss2, outp);
    }
    (void)in_sizes; (void)n_in; (void)out_size;
}

// Round 10
// 631.207 us; speedup vs baseline: 3.1425x; 1.0677x over previous
//
#include <hip/hip_runtime.h>
#include <hip/hip_fp16.h>
#include <hip/hip_bf16.h>

// shooting_model: B=16, H=W=512, L=10, MU=0.05, KS=7, SIGMA=2
// R15: algebraic restructure -- one f32 accumulated-residual plane B and
// phi0 replace the 9-plane phi/residual history (error enters at MU^2/L).
// R16: v-blur hoisted into sTV (cooperative pass).
// R17: step fused into dynamics kernel; def never touches memory.
// R18: channel-packed (f2) blurs -> v_pk_fma_f32, b64 LDS ops.
// R19: register-blocked passes (2 elems/thread, shared LDS reads).
// R20: REGISTER-PATCH final stencil. Wave-level accounting shows the LDS
// pipe saturated (~137K of 155K cyc/CU) with the final div-stencil section
// the largest consumer (52 DS instr/wave). The px-pair's 12-point stencils
// share a 3x4 patch: load Rp[3][4] (sR) + Vp[3][4] (sTV2, f2) once into
// registers, evaluate both pixels from registers -> 24 DS instr/wave.
// Same loads/FMA order -> bit-identical numerics.

namespace {
constexpr int W_ = 512, H_ = 512, L_ = 10;
constexpr int HW_ = W_ * H_;          // 1<<18
constexpr int N_  = 16 * HW_;         // 4194304
constexpr float INVL = 0.1f;
constexpr float MU2L = 2.5e-4f;       // MU^2/L

typedef float f2 __attribute__((ext_vector_type(2)));

__device__ __constant__ f2 GW2[7] = {
    {0.07015933f, 0.07015933f}, {0.13107488f, 0.13107488f},
    {0.19071282f, 0.19071282f}, {0.21610594f, 0.21610594f},
    {0.19071282f, 0.19071282f}, {0.13107488f, 0.13107488f},
    {0.07015933f, 0.07015933f}};

struct BilL {                          // floor ints + weights
    int x0, y0;
    float w00, w01, w10, w11;
};
struct Bil {                           // + clamped float corner coords
    BilL l;
    float xc0, xc1, yc0, yc1;
};

__device__ __forceinline__ BilL mk_lite(float gx, float gy) {
    gx = fminf(fmaxf(gx, -1.0e9f), 1.0e9f);
    gy = fminf(fmaxf(gy, -1.0e9f), 1.0e9f);
    float x0f = floorf(gx), y0f = floorf(gy);
    float wx = gx - x0f, wy = gy - y0f;
    int x0 = (int)x0f, y0 = (int)y0f;
    float vx0 = ((unsigned)x0 < (unsigned)W_) ? 1.f : 0.f;
    float vx1 = ((unsigned)(x0 + 1) < (unsigned)W_) ? 1.f : 0.f;
    float vy0 = ((unsigned)y0 < (unsigned)H_) ? 1.f : 0.f;
    float vy1 = ((unsigned)(y0 + 1) < (unsigned)H_) ? 1.f : 0.f;
    BilL b;
    b.x0 = x0; b.y0 = y0;
    b.w00 = (1.f - wx) * (1.f - wy) * vx0 * vy0;
    b.w01 = wx * (1.f - wy) * vx1 * vy0;
    b.w10 = (1.f - wx) * wy * vx0 * vy1;
    b.w11 = wx * wy * vx1 * vy1;
    return b;
}

__device__ __forceinline__ Bil mk_full(float gx, float gy) {
    Bil b;
    b.l = mk_lite(gx, gy);
    int xc0 = min(max(b.l.x0, 0), W_ - 1), xc1 = min(max(b.l.x0 + 1, 0), W_ - 1);
    int yc0 = min(max(b.l.y0, 0), H_ - 1), yc1 = min(max(b.l.y0 + 1, 0), H_ - 1);
    b.xc0 = (float)xc0; b.xc1 = (float)xc1;
    b.yc0 = (float)yc0; b.yc1 = (float)yc1;
    return b;
}

__device__ __forceinline__ void gidx(const BilL& b, int& i00, int& i01,
                                     int& i10, int& i11) {
    int xc0 = min(max(b.x0, 0), W_ - 1), xc1 = min(max(b.x0 + 1, 0), W_ - 1);
    int yc0 = min(max(b.y0, 0), H_ - 1), yc1 = min(max(b.y0 + 1, 0), H_ - 1);
    i00 = yc0 * W_ + xc0; i01 = yc0 * W_ + xc1;
    i10 = yc1 * W_ + xc0; i11 = yc1 * W_ + xc1;
}

__device__ __forceinline__ float2 upk(unsigned u) {
    __half2 h; *reinterpret_cast<unsigned*>(&h) = u;
    return __half22float2(h);
}
__device__ __forceinline__ unsigned pkh(float a, float b) {
    __half2 h = __floats2half2_rn(a, b);
    return *reinterpret_cast<unsigned*>(&h);
}

// phi buffers store DISPLACEMENT (id - phi_abs) as half2, like def.
__device__ __forceinline__ void warp_from(unsigned v00, unsigned v01,
                                          unsigned v10, unsigned v11,
                                          const Bil& bw, float& wxo, float& wyo) {
    float2 s00 = upk(v00), s01 = upk(v01), s10 = upk(v10), s11 = upk(v11);
    wxo = bw.l.w00 * (bw.xc0 - s00.x) + bw.l.w01 * (bw.xc1 - s01.x)
        + bw.l.w10 * (bw.xc0 - s10.x) + bw.l.w11 * (bw.xc1 - s11.x);
    wyo = bw.l.w00 * (bw.yc0 - s00.y) + bw.l.w01 * (bw.yc0 - s01.y)
        + bw.l.w10 * (bw.yc1 - s10.y) + bw.l.w11 * (bw.yc1 - s11.y);
}

// pack src/seg f32 -> interleaved float2 (exact copy)
__global__ __launch_bounds__(256) void k_pack2(const float* __restrict__ src,
                                               const float* __restrict__ seg,
                                               float2* __restrict__ out) {
    int idx = blockIdx.x * 256 + threadIdx.x;
    out[idx] = make_float2(src[idx], seg[idx]);
}

// Fused step: dynamics (sobel -> separable blur -> v; rnext = r - div/L)
// + warp/B-update/output. def = v/L stays in LDS.
// FIRST: i==0 (phi0 == def, B = r_1). WR: write p0_new/Bnew (i<9).
template <int FIRST, int WR>
__global__ __launch_bounds__(256) void k_F(const float* __restrict__ img,
                                           const float* __restrict__ rin,
                                           float* __restrict__ rnext_f,
                                           const unsigned* __restrict__ p0_old,
                                           unsigned* __restrict__ p0_new,
                                           const float* __restrict__ Bold,
                                           float* __restrict__ Bnew,
                                           const float2* __restrict__ ss2,
                                           float* __restrict__ outp) {
    __shared__ float sI[26][43];
    __shared__ float sR[24][41];
    __shared__ f2 sS2[24][41];          // channel-packed sobel products
    __shared__ f2 sTH2[24][35];         // channel-packed h-blur
    // v-blur result, channel-packed; aliases sS2 (dead after h-blur)
    f2 (*sTV2)[35] = reinterpret_cast<f2 (*)[35]>(&sS2[0][0]);
    const int t = threadIdx.x;
    const int x0 = blockIdx.x * 32, y0 = blockIdx.y * 16, b = blockIdx.z;
    const size_t base = (size_t)b * HW_;
    const float* ip = img + base;
    const float* rp = rin + base;
    for (int u = t; u < 26 * 42; u += 256) {
        int r = u / 42, c = u % 42;
        int gy = min(max(y0 - 5 + r, 0), H_ - 1);
        int gx = min(max(x0 - 5 + c, 0), W_ - 1);
        sI[r][c] = ip[gy * W_ + gx];
    }
    for (int u = t; u < 24 * 40; u += 256) {
        int r = u / 40, c = u % 40;
        int gy = y0 - 4 + r, gx = x0 - 4 + c;
        sR[r][c] = ((unsigned)gy < (unsigned)H_ && (unsigned)gx < (unsigned)W_)
                 ? rp[gy * W_ + gx] : 0.f;
    }
    __syncthreads();
    // s = -r * sobel(img), 2 elems/thread (shared sI reads)
    for (int u = t; u < 24 * 20; u += 256) {
        int r = u / 20, cp = u - (u / 20) * 20;
        int c = cp * 2;
        float a00 = sI[r][c],     a01 = sI[r][c + 1];
        float a02 = sI[r][c + 2], a03 = sI[r][c + 3];
        float a10 = sI[r + 1][c],     a11 = sI[r + 1][c + 1];
        float a12 = sI[r + 1][c + 2], a13 = sI[r + 1][c + 3];
        float a20 = sI[r + 2][c],     a21 = sI[r + 2][c + 1];
        float a22 = sI[r + 2][c + 2], a23 = sI[r + 2][c + 3];
        float rv0 = sR[r][c], rv1 = sR[r][c + 1];
        float gx0 = ((a02 - a00) + 2.f * (a12 - a10) + (a22 - a20)) * 0.125f;
        float gy0 = ((a20 - a00) + 2.f * (a21 - a01) + (a22 - a02)) * 0.125f;
        float gx1 = ((a03 - a01) + 2.f * (a13 - a11) + (a23 - a21)) * 0.125f;
        float gy1 = ((a21 - a01) + 2.f * (a22 - a02) + (a23 - a03)) * 0.125f;
        f2 s0; s0.x = -rv0 * gx0; s0.y = -rv0 * gy0;
        f2 s1; s1.x = -rv1 * gx1; s1.y = -rv1 * gy1;
        sS2[r][c] = s0; sS2[r][c + 1] = s1;
    }
    __syncthreads();
    // th = h-blur(s), 2 elems/thread (8 shared b64 reads)
    for (int u = t; u < 24 * 17; u += 256) {
        int r = u / 17, cp = u - (u / 17) * 17;
        int c = cp * 2;
        f2 w0 = sS2[r][c],     w1 = sS2[r][c + 1], w2 = sS2[r][c + 2];
        f2 w3 = sS2[r][c + 3], w4 = sS2[r][c + 4], w5 = sS2[r][c + 5];
        f2 w6 = sS2[r][c + 6], w7 = sS2[r][c + 7];
        f2 a0 = {0.f, 0.f}, a1 = {0.f, 0.f};
        a0 = __builtin_elementwise_fma(GW2[0], w0, a0);
        a1 = __builtin_elementwise_fma(GW2[0], w1, a1);
        a0 = __builtin_elementwise_fma(GW2[1], w1, a0);
        a1 = __builtin_elementwise_fma(GW2[1], w2, a1);
        a0 = __builtin_elementwise_fma(GW2[2], w2, a0);
        a1 = __builtin_elementwise_fma(GW2[2], w3, a1);
        a0 = __builtin_elementwise_fma(GW2[3], w3, a0);
        a1 = __builtin_elementwise_fma(GW2[3], w4, a1);
        a0 = __builtin_elementwise_fma(GW2[4], w4, a0);
        a1 = __builtin_elementwise_fma(GW2[4], w5, a1);
        a0 = __builtin_elementwise_fma(GW2[5], w5, a0);
        a1 = __builtin_elementwise_fma(GW2[5], w6, a1);
        a0 = __builtin_elementwise_fma(GW2[6], w6, a0);
        a1 = __builtin_elementwise_fma(GW2[6], w7, a1);
        sTH2[r][c] = a0; sTH2[r][c + 1] = a1;
    }
    __syncthreads();                           // sS2 dead; sTV2 may overwrite
    // v = v-blur(th), 2 vertically-adjacent elems/thread (8 shared reads)
    for (int u = t; u < 9 * 34; u += 256) {
        int rpair = u / 34, c = u - rpair * 34;
        int r = rpair * 2;
        f2 w0 = sTH2[r][c],     w1 = sTH2[r + 1][c], w2 = sTH2[r + 2][c];
        f2 w3 = sTH2[r + 3][c], w4 = sTH2[r + 4][c], w5 = sTH2[r + 5][c];
        f2 w6 = sTH2[r + 6][c], w7 = sTH2[r + 7][c];
        f2 a0 = {0.f, 0.f}, a1 = {0.f, 0.f};
        a0 = __builtin_elementwise_fma(GW2[0], w0, a0);
        a1 = __builtin_elementwise_fma(GW2[0], w1, a1);
        a0 = __builtin_elementwise_fma(GW2[1], w1, a0);
        a1 = __builtin_elementwise_fma(GW2[1], w2, a1);
        a0 = __builtin_elementwise_fma(GW2[2], w2, a0);
        a1 = __builtin_elementwise_fma(GW2[2], w3, a1);
        a0 = __builtin_elementwise_fma(GW2[3], w3, a0);
        a1 = __builtin_elementwise_fma(GW2[3], w4, a1);
        a0 = __builtin_elementwise_fma(GW2[4], w4, a0);
        a1 = __builtin_elementwise_fma(GW2[4], w5, a1);
        a0 = __builtin_elementwise_fma(GW2[5], w5, a0);
        a1 = __builtin_elementwise_fma(GW2[5], w6, a1);
        a0 = __builtin_elementwise_fma(GW2[6], w6, a0);
        a1 = __builtin_elementwise_fma(GW2[6], w7, a1);
        sTV2[r][c] = a0; sTV2[r + 1][c] = a1;
    }
    __syncthreads();
    const int tx = t & 15, ty = t >> 4;        // 2 px/thread in x
    const int y = y0 + ty;

    // R20: shared register patches for the px pair (3 rows x 4 cols)
    float Rp[3][4]; f2 Vp[3][4];
#pragma unroll
    for (int dy = 0; dy < 3; dy++)
#pragma unroll
        for (int dx = 0; dx < 4; dx++) {
            Rp[dy][dx] = sR[ty + 3 + dy][tx * 2 + 3 + dx];
            Vp[dy][dx] = sTV2[ty + dy][tx * 2 + dx];
        }

    float rn2[2]; unsigned ph2[2];
#pragma unroll
    for (int px = 0; px < 2; px++) {
        const int x = x0 + tx * 2 + px;
        auto Vv = [&](int ch, int dy, int dx) -> float {
            f2 v = Vp[dy + 1][px + dx + 1];
            return ch ? v.y : v.x;
        };
        auto Wt = [&](int ch, int dy, int dx) -> float {
            int yy = y + dy, xx = x + dx;
            if ((unsigned)yy >= (unsigned)H_ || (unsigned)xx >= (unsigned)W_) return 0.f;
            return Rp[dy + 1][px + dx + 1] * Vv(ch, dy, dx);
        };
        float f = (Wt(0, -1, 1) - Wt(0, -1, -1)) + 2.f * (Wt(0, 0, 1) - Wt(0, 0, -1))
                + (Wt(0, 1, 1) - Wt(0, 1, -1))
                + (Wt(1, 1, -1) - Wt(1, -1, -1)) + 2.f * (Wt(1, 1, 0) - Wt(1, -1, 0))
                + (Wt(1, 1, 1) - Wt(1, -1, 1));
        f *= 0.0125f;                          // (1/8 div-kernel) * (1/L)
        rn2[px] = Rp[1][px + 1] - f;
        ph2[px] = pkh(Vv(0, 0, 0) * INVL, Vv(1, 0, 0) * INVL);
    }
    const int idx0 = b * HW_ + y * W_ + x0 + tx * 2; // even
    *reinterpret_cast<float2*>(rnext_f + idx0) = make_float2(rn2[0], rn2[1]);

    // ---- fused step tail: warp phi0 / update B / assemble output ----
    const float2* ssp = ss2 + base;
    float Bv[2], ov[2]; unsigned p0w[2];
#pragma unroll
    for (int px = 0; px < 2; px++) {
        const int x = x0 + tx * 2 + px;
        float2 d = upk(ph2[px]);               // same half2 round-trip as R16
        Bil bw = mk_full((float)x - d.x, (float)y - d.y);
        float Bx = rn2[px];
        BilL q = bw.l;
        if (!FIRST) {
            int i00, i01, i10, i11; gidx(bw.l, i00, i01, i10, i11);
            const unsigned* pp = p0_old + base;
            unsigned s00 = pp[i00], s01 = pp[i01], s10 = pp[i10], s11 = pp[i11];
            const float* Bp = Bold + base;
            float f00 = Bp[i00], f01 = Bp[i01], f10 = Bp[i10], f11 = Bp[i11];
            float wx, wy;
            warp_from(s00, s01, s10, s11, bw, wx, wy);
            Bx += f00 * bw.l.w00 + f01 * bw.l.w01 + f10 * bw.l.w10 + f11 * bw.l.w11;
            if (WR) p0w[px] = pkh((float)x - wx, (float)y - wy);
            q = mk_lite(wx, wy);
        } else {
            if (WR) p0w[px] = ph2[px];         // phi0^{(0)} = def_0
        }
        int i00, i01, i10, i11; gidx(q, i00, i01, i10, i11);
        float2 c00 = ssp[i00], c01 = ssp[i01], c10 = ssp[i10], c11 = ssp[i11];
        float si = c00.x * q.w00 + c01.x * q.w01 + c10.x * q.w10 + c11.x * q.w11;
        float sg = c00.y * q.w00 + c01.y * q.w01 + c10.y * q.w10 + c11.y * q.w11;
        Bv[px] = Bx;
        ov[px] = si + Bx * MU2L * sg;
    }
    if (WR) {
        *reinterpret_cast<uint2*>(p0_new + idx0) = make_uint2(p0w[0], p0w[1]);
        *reinterpret_cast<float2*>(Bnew + idx0) = make_float2(Bv[0], Bv[1]);
    }
    *reinterpret_cast<float2*>(outp + idx0) = make_float2(ov[0], ov[1]);
}

// diagnostic fallback (normalized error 0.96 signature == ws too small)
__global__ __launch_bounds__(256) void k_copy(const float* __restrict__ a,
                                              float* __restrict__ o) {
    int idx = blockIdx.x * 256 + threadIdx.x;
    o[idx] = a[idx];
}

} // namespace

extern "C" void kernel_launch(void* const* d_in, const int* in_sizes, int n_in,
                              void* d_out, int out_size, void* d_ws, size_t ws_size,
                              hipStream_t stream) {
    const float* source = (const float*)d_in[0];
    const float* z0     = (const float*)d_in[1];
    const float* seg    = (const float*)d_in[2];
    float* out = (float*)d_out;

    const size_t UNIT = (size_t)N_ * 4;          // 16 MiB
    dim3 blk(256), g1(N_ / 256), gA(16, 32, 16);

    if (ws_size < 10 * UNIT) {
        hipLaunchKernelGGL(k_copy, g1, blk, 0, stream, source, out);
        return;
    }

    char* basep = (char*)d_ws;
    float2*   ss2    = (float2*)basep;                        // u0,u1
    float*    imgA   = (float*)(basep + 2 * UNIT);            // u2 (even i)
    unsigned* phb[2] = {(unsigned*)(basep + 4 * UNIT),        // u4
                        (unsigned*)(basep + 5 * UNIT)};       // u5
    float*    Bb[2]  = {(float*)(basep + 6 * UNIT),           // u6
                        (float*)(basep + 7 * UNIT)};          // u7
    float*    rnb[2] = {(float*)(basep + 8 * UNIT),           // u8
                        (float*)(basep + 9 * UNIT)};          // u9

    hipLaunchKernelGGL(k_pack2, g1, blk, 0, stream, source, seg, ss2);

    // F0: img=source, rin=z0 -> writes rnb[0], phb[0], Bb[0], imgA
    hipLaunchKernelGGL((k_F<1, 1>), gA, blk, 0, stream,
                       source, z0, rnb[0], (const unsigned*)nullptr, phb[0],
                       (const float*)nullptr, Bb[0], (const float2*)ss2, imgA);

    // F1..F9: odd i -> writes d_out; even i -> writes imgA. F9 -> d_out.
    for (int i = 1; i < L_; i++) {
        const float* img = (i & 1) ? imgA : out;   // written by F_{i-1}
        float* outp      = (i & 1) ? out : imgA;
        const float* rin = rnb[(i - 1) & 1];
        float* rn_w      = rnb[i & 1];
        const unsigned* p0o = phb[(i - 1) & 1];
        unsigned* p0n       = phb[i & 1];
        const float* Bo  = Bb[(i - 1) & 1];
        float* Bn        = Bb[i & 1];
        if (i < L_ - 1)
            hipLaunchKernelGGL((k_F<0, 1>), gA, blk, 0, stream,
                               img, rin, rn_w, p0o, p0n, Bo, Bn,
                               (const float2*)ss2, outp);
        else
            hipLaunchKernelGGL((k_F<0, 0>), gA, blk, 0, stream,
                               img, rin, rn_w, p0o, p0n, Bo, Bn,
                               (const float2*)ss2, outp);
    }
    (void)in_sizes; (void)n_in; (void)out_size;
}

// Round 11
// 613.253 us; speedup vs baseline: 3.2345x; 1.0293x over previous
//
#include <hip/hip_runtime.h>
#include <hip/hip_fp16.h>
#include <hip/hip_bf16.h>

// shooting_model: B=16, H=W=512, L=10, MU=0.05, KS=7, SIGMA=2
// R15: algebraic restructure -- one f32 accumulated-residual plane B and
// phi0 replace the 9-plane phi/residual history (error enters at MU^2/L).
// R16: v-blur hoisted into sTV (cooperative pass).
// R17: step fused into dynamics kernel; def never touches memory.
// R18: channel-packed (f2) blurs -> v_pk_fma_f32, b64 LDS ops.
// R19: register-blocked passes (2 elems/thread, shared LDS reads).
// R20: register-patch final stencil (Rp/Vp 3x4 per thread).
// R21: DEEP register blocking -- LDS pipe measured ~85% busy (360 wave-DS
// per block; sobel 120, final 96, h-blur 64, v-blur 48). sobel 2x2 block
// (16+4 reads/4 elems, 240 threads exact), h-blur quad-col and v-blur
// quad-row (10 reads/4 outputs). -63 wave-DS (-17% LDS issue). Loaded
// values and per-elem FMA order unchanged -> bit-identical numerics.

namespace {
constexpr int W_ = 512, H_ = 512, L_ = 10;
constexpr int HW_ = W_ * H_;          // 1<<18
constexpr int N_  = 16 * HW_;         // 4194304
constexpr float INVL = 0.1f;
constexpr float MU2L = 2.5e-4f;       // MU^2/L

typedef float f2 __attribute__((ext_vector_type(2)));

__device__ __constant__ f2 GW2[7] = {
    {0.07015933f, 0.07015933f}, {0.13107488f, 0.13107488f},
    {0.19071282f, 0.19071282f}, {0.21610594f, 0.21610594f},
    {0.19071282f, 0.19071282f}, {0.13107488f, 0.13107488f},
    {0.07015933f, 0.07015933f}};

struct BilL {                          // floor ints + weights
    int x0, y0;
    float w00, w01, w10, w11;
};
struct Bil {                           // + clamped float corner coords
    BilL l;
    float xc0, xc1, yc0, yc1;
};

__device__ __forceinline__ BilL mk_lite(float gx, float gy) {
    gx = fminf(fmaxf(gx, -1.0e9f), 1.0e9f);
    gy = fminf(fmaxf(gy, -1.0e9f), 1.0e9f);
    float x0f = floorf(gx), y0f = floorf(gy);
    float wx = gx - x0f, wy = gy - y0f;
    int x0 = (int)x0f, y0 = (int)y0f;
    float vx0 = ((unsigned)x0 < (unsigned)W_) ? 1.f : 0.f;
    float vx1 = ((unsigned)(x0 + 1) < (unsigned)W_) ? 1.f : 0.f;
    float vy0 = ((unsigned)y0 < (unsigned)H_) ? 1.f : 0.f;
    float vy1 = ((unsigned)(y0 + 1) < (unsigned)H_) ? 1.f : 0.f;
    BilL b;
    b.x0 = x0; b.y0 = y0;
    b.w00 = (1.f - wx) * (1.f - wy) * vx0 * vy0;
    b.w01 = wx * (1.f - wy) * vx1 * vy0;
    b.w10 = (1.f - wx) * wy * vx0 * vy1;
    b.w11 = wx * wy * vx1 * vy1;
    return b;
}

__device__ __forceinline__ Bil mk_full(float gx, float gy) {
    Bil b;
    b.l = mk_lite(gx, gy);
    int xc0 = min(max(b.l.x0, 0), W_ - 1), xc1 = min(max(b.l.x0 + 1, 0), W_ - 1);
    int yc0 = min(max(b.l.y0, 0), H_ - 1), yc1 = min(max(b.l.y0 + 1, 0), H_ - 1);
    b.xc0 = (float)xc0; b.xc1 = (float)xc1;
    b.yc0 = (float)yc0; b.yc1 = (float)yc1;
    return b;
}

__device__ __forceinline__ void gidx(const BilL& b, int& i00, int& i01,
                                     int& i10, int& i11) {
    int xc0 = min(max(b.x0, 0), W_ - 1), xc1 = min(max(b.x0 + 1, 0), W_ - 1);
    int yc0 = min(max(b.y0, 0), H_ - 1), yc1 = min(max(b.y0 + 1, 0), H_ - 1);
    i00 = yc0 * W_ + xc0; i01 = yc0 * W_ + xc1;
    i10 = yc1 * W_ + xc0; i11 = yc1 * W_ + xc1;
}

__device__ __forceinline__ float2 upk(unsigned u) {
    __half2 h; *reinterpret_cast<unsigned*>(&h) = u;
    return __half22float2(h);
}
__device__ __forceinline__ unsigned pkh(float a, float b) {
    __half2 h = __floats2half2_rn(a, b);
    return *reinterpret_cast<unsigned*>(&h);
}

// phi buffers store DISPLACEMENT (id - phi_abs) as half2, like def.
__device__ __forceinline__ void warp_from(unsigned v00, unsigned v01,
                                          unsigned v10, unsigned v11,
                                          const Bil& bw, float& wxo, float& wyo) {
    float2 s00 = upk(v00), s01 = upk(v01), s10 = upk(v10), s11 = upk(v11);
    wxo = bw.l.w00 * (bw.xc0 - s00.x) + bw.l.w01 * (bw.xc1 - s01.x)
        + bw.l.w10 * (bw.xc0 - s10.x) + bw.l.w11 * (bw.xc1 - s11.x);
    wyo = bw.l.w00 * (bw.yc0 - s00.y) + bw.l.w01 * (bw.yc0 - s01.y)
        + bw.l.w10 * (bw.yc1 - s10.y) + bw.l.w11 * (bw.yc1 - s11.y);
}

// pack src/seg f32 -> interleaved float2 (exact copy)
__global__ __launch_bounds__(256) void k_pack2(const float* __restrict__ src,
                                               const float* __restrict__ seg,
                                               float2* __restrict__ out) {
    int idx = blockIdx.x * 256 + threadIdx.x;
    out[idx] = make_float2(src[idx], seg[idx]);
}

// Fused step: dynamics (sobel -> separable blur -> v; rnext = r - div/L)
// + warp/B-update/output. def = v/L stays in LDS.
// FIRST: i==0 (phi0 == def, B = r_1). WR: write p0_new/Bnew (i<9).
template <int FIRST, int WR>
__global__ __launch_bounds__(256) void k_F(const float* __restrict__ img,
                                           const float* __restrict__ rin,
                                           float* __restrict__ rnext_f,
                                           const unsigned* __restrict__ p0_old,
                                           unsigned* __restrict__ p0_new,
                                           const float* __restrict__ Bold,
                                           float* __restrict__ Bnew,
                                           const float2* __restrict__ ss2,
                                           float* __restrict__ outp) {
    __shared__ float sI[26][43];
    __shared__ float sR[24][41];
    __shared__ f2 sS2[24][41];          // channel-packed sobel products
    __shared__ f2 sTH2[24][35];         // channel-packed h-blur
    // v-blur result, channel-packed; aliases sS2 (dead after h-blur)
    f2 (*sTV2)[35] = reinterpret_cast<f2 (*)[35]>(&sS2[0][0]);
    const int t = threadIdx.x;
    const int x0 = blockIdx.x * 32, y0 = blockIdx.y * 16, b = blockIdx.z;
    const size_t base = (size_t)b * HW_;
    const float* ip = img + base;
    const float* rp = rin + base;
    for (int u = t; u < 26 * 42; u += 256) {
        int r = u / 42, c = u % 42;
        int gy = min(max(y0 - 5 + r, 0), H_ - 1);
        int gx = min(max(x0 - 5 + c, 0), W_ - 1);
        sI[r][c] = ip[gy * W_ + gx];
    }
    for (int u = t; u < 24 * 40; u += 256) {
        int r = u / 40, c = u % 40;
        int gy = y0 - 4 + r, gx = x0 - 4 + c;
        sR[r][c] = ((unsigned)gy < (unsigned)H_ && (unsigned)gx < (unsigned)W_)
                 ? rp[gy * W_ + gx] : 0.f;
    }
    __syncthreads();
    // s = -r * sobel(img), 2x2 register block: 240 threads, 1 iter each
    if (t < 240) {
        int rq = t / 20, cq = t - rq * 20;
        int r = rq * 2, c = cq * 2;
        float a00 = sI[r][c],     a01 = sI[r][c + 1];
        float a02 = sI[r][c + 2], a03 = sI[r][c + 3];
        float a10 = sI[r + 1][c],     a11 = sI[r + 1][c + 1];
        float a12 = sI[r + 1][c + 2], a13 = sI[r + 1][c + 3];
        float a20 = sI[r + 2][c],     a21 = sI[r + 2][c + 1];
        float a22 = sI[r + 2][c + 2], a23 = sI[r + 2][c + 3];
        float a30 = sI[r + 3][c],     a31 = sI[r + 3][c + 1];
        float a32 = sI[r + 3][c + 2], a33 = sI[r + 3][c + 3];
        float rv00 = sR[r][c],     rv01 = sR[r][c + 1];
        float rv10 = sR[r + 1][c], rv11 = sR[r + 1][c + 1];
        float gx0 = ((a02 - a00) + 2.f * (a12 - a10) + (a22 - a20)) * 0.125f;
        float gy0 = ((a20 - a00) + 2.f * (a21 - a01) + (a22 - a02)) * 0.125f;
        float gx1 = ((a03 - a01) + 2.f * (a13 - a11) + (a23 - a21)) * 0.125f;
        float gy1 = ((a21 - a01) + 2.f * (a22 - a02) + (a23 - a03)) * 0.125f;
        float gx2 = ((a12 - a10) + 2.f * (a22 - a20) + (a32 - a30)) * 0.125f;
        float gy2 = ((a30 - a10) + 2.f * (a31 - a11) + (a32 - a12)) * 0.125f;
        float gx3 = ((a13 - a11) + 2.f * (a23 - a21) + (a33 - a31)) * 0.125f;
        float gy3 = ((a31 - a11) + 2.f * (a32 - a12) + (a33 - a13)) * 0.125f;
        f2 s0; s0.x = -rv00 * gx0; s0.y = -rv00 * gy0;
        f2 s1; s1.x = -rv01 * gx1; s1.y = -rv01 * gy1;
        f2 s2; s2.x = -rv10 * gx2; s2.y = -rv10 * gy2;
        f2 s3; s3.x = -rv11 * gx3; s3.y = -rv11 * gy3;
        sS2[r][c] = s0; sS2[r][c + 1] = s1;
        sS2[r + 1][c] = s2; sS2[r + 1][c + 1] = s3;
    }
    __syncthreads();
    // th = h-blur(s), quad-col: 216 threads, 10 reads / 4 outputs
    if (t < 24 * 9) {
        int r = t / 9, q = t - (t / 9) * 9;
        int c = q * 4;
        f2 w[10];
#pragma unroll
        for (int k = 0; k < 10; k++)
            w[k] = (c + k < 40) ? sS2[r][c + k] : (f2){0.f, 0.f};
#pragma unroll
        for (int j = 0; j < 4; j++) {
            if (c + j < 34) {
                f2 a = {0.f, 0.f};
#pragma unroll
                for (int k = 0; k < 7; k++)
                    a = __builtin_elementwise_fma(GW2[k], w[j + k], a);
                sTH2[r][c + j] = a;
            }
        }
    }
    __syncthreads();                           // sS2 dead; sTV2 may overwrite
    // v = v-blur(th), quad-row: 170 threads, 10 reads / 4 outputs
    if (t < 5 * 34) {
        int p = t / 34, c = t - (t / 34) * 34;
        int r = p * 4;
        f2 w[10];
#pragma unroll
        for (int k = 0; k < 10; k++)
            w[k] = (r + k < 24) ? sTH2[r + k][c] : (f2){0.f, 0.f};
#pragma unroll
        for (int j = 0; j < 4; j++) {
            if (r + j < 18) {
                f2 a = {0.f, 0.f};
#pragma unroll
                for (int k = 0; k < 7; k++)
                    a = __builtin_elementwise_fma(GW2[k], w[j + k], a);
                sTV2[r + j][c] = a;
            }
        }
    }
    __syncthreads();
    const int tx = t & 15, ty = t >> 4;        // 2 px/thread in x
    const int y = y0 + ty;

    // shared register patches for the px pair (3 rows x 4 cols)
    float Rp[3][4]; f2 Vp[3][4];
#pragma unroll
    for (int dy = 0; dy < 3; dy++)
#pragma unroll
        for (int dx = 0; dx < 4; dx++) {
            Rp[dy][dx] = sR[ty + 3 + dy][tx * 2 + 3 + dx];
            Vp[dy][dx] = sTV2[ty + dy][tx * 2 + dx];
        }

    float rn2[2]; unsigned ph2[2];
#pragma unroll
    for (int px = 0; px < 2; px++) {
        const int x = x0 + tx * 2 + px;
        auto Vv = [&](int ch, int dy, int dx) -> float {
            f2 v = Vp[dy + 1][px + dx + 1];
            return ch ? v.y : v.x;
        };
        auto Wt = [&](int ch, int dy, int dx) -> float {
            int yy = y + dy, xx = x + dx;
            if ((unsigned)yy >= (unsigned)H_ || (unsigned)xx >= (unsigned)W_) return 0.f;
            return Rp[dy + 1][px + dx + 1] * Vv(ch, dy, dx);
        };
        float f = (Wt(0, -1, 1) - Wt(0, -1, -1)) + 2.f * (Wt(0, 0, 1) - Wt(0, 0, -1))
                + (Wt(0, 1, 1) - Wt(0, 1, -1))
                + (Wt(1, 1, -1) - Wt(1, -1, -1)) + 2.f * (Wt(1, 1, 0) - Wt(1, -1, 0))
                + (Wt(1, 1, 1) - Wt(1, -1, 1));
        f *= 0.0125f;                          // (1/8 div-kernel) * (1/L)
        rn2[px] = Rp[1][px + 1] - f;
        ph2[px] = pkh(Vv(0, 0, 0) * INVL, Vv(1, 0, 0) * INVL);
    }
    const int idx0 = b * HW_ + y * W_ + x0 + tx * 2; // even
    *reinterpret_cast<float2*>(rnext_f + idx0) = make_float2(rn2[0], rn2[1]);

    // ---- fused step tail: warp phi0 / update B / assemble output ----
    const float2* ssp = ss2 + base;
    float Bv[2], ov[2]; unsigned p0w[2];
#pragma unroll
    for (int px = 0; px < 2; px++) {
        const int x = x0 + tx * 2 + px;
        float2 d = upk(ph2[px]);               // same half2 round-trip as R16
        Bil bw = mk_full((float)x - d.x, (float)y - d.y);
        float Bx = rn2[px];
        BilL q = bw.l;
        if (!FIRST) {
            int i00, i01, i10, i11; gidx(bw.l, i00, i01, i10, i11);
            const unsigned* pp = p0_old + base;
            unsigned s00 = pp[i00], s01 = pp[i01], s10 = pp[i10], s11 = pp[i11];
            const float* Bp = Bold + base;
            float f00 = Bp[i00], f01 = Bp[i01], f10 = Bp[i10], f11 = Bp[i11];
            float wx, wy;
            warp_from(s00, s01, s10, s11, bw, wx, wy);
            Bx += f00 * bw.l.w00 + f01 * bw.l.w01 + f10 * bw.l.w10 + f11 * bw.l.w11;
            if (WR) p0w[px] = pkh((float)x - wx, (float)y - wy);
            q = mk_lite(wx, wy);
        } else {
            if (WR) p0w[px] = ph2[px];         // phi0^{(0)} = def_0
        }
        int i00, i01, i10, i11; gidx(q, i00, i01, i10, i11);
        float2 c00 = ssp[i00], c01 = ssp[i01], c10 = ssp[i10], c11 = ssp[i11];
        float si = c00.x * q.w00 + c01.x * q.w01 + c10.x * q.w10 + c11.x * q.w11;
        float sg = c00.y * q.w00 + c01.y * q.w01 + c10.y * q.w10 + c11.y * q.w11;
        Bv[px] = Bx;
        ov[px] = si + Bx * MU2L * sg;
    }
    if (WR) {
        *reinterpret_cast<uint2*>(p0_new + idx0) = make_uint2(p0w[0], p0w[1]);
        *reinterpret_cast<float2*>(Bnew + idx0) = make_float2(Bv[0], Bv[1]);
    }
    *reinterpret_cast<float2*>(outp + idx0) = make_float2(ov[0], ov[1]);
}

// diagnostic fallback (normalized error 0.96 signature == ws too small)
__global__ __launch_bounds__(256) void k_copy(const float* __restrict__ a,
                                              float* __restrict__ o) {
    int idx = blockIdx.x * 256 + threadIdx.x;
    o[idx] = a[idx];
}

} // namespace

extern "C" void kernel_launch(void* const* d_in, const int* in_sizes, int n_in,
                              void* d_out, int out_size, void* d_ws, size_t ws_size,
                              hipStream_t stream) {
    const float* source = (const float*)d_in[0];
    const float* z0     = (const float*)d_in[1];
    const float* seg    = (const float*)d_in[2];
    float* out = (float*)d_out;

    const size_t UNIT = (size_t)N_ * 4;          // 16 MiB
    dim3 blk(256), g1(N_ / 256), gA(16, 32, 16);

    if (ws_size < 10 * UNIT) {
        hipLaunchKernelGGL(k_copy, g1, blk, 0, stream, source, out);
        return;
    }

    char* basep = (char*)d_ws;
    float2*   ss2    = (float2*)basep;                        // u0,u1
    float*    imgA   = (float*)(basep + 2 * UNIT);            // u2 (even i)
    unsigned* phb[2] = {(unsigned*)(basep + 4 * UNIT),        // u4
                        (unsigned*)(basep + 5 * UNIT)};       // u5
    float*    Bb[2]  = {(float*)(basep + 6 * UNIT),           // u6
                        (float*)(basep + 7 * UNIT)};          // u7
    float*    rnb[2] = {(float*)(basep + 8 * UNIT),           // u8
                        (float*)(basep + 9 * UNIT)};          // u9

    hipLaunchKernelGGL(k_pack2, g1, blk, 0, stream, source, seg, ss2);

    // F0: img=source, rin=z0 -> writes rnb[0], phb[0], Bb[0], imgA
    hipLaunchKernelGGL((k_F<1, 1>), gA, blk, 0, stream,
                       source, z0, rnb[0], (const unsigned*)nullptr, phb[0],
                       (const float*)nullptr, Bb[0], (const float2*)ss2, imgA);

    // F1..F9: odd i -> writes d_out; even i -> writes imgA. F9 -> d_out.
    for (int i = 1; i < L_; i++) {
        const float* img = (i & 1) ? imgA : out;   // written by F_{i-1}
        float* outp      = (i & 1) ? out : imgA;
        const float* rin = rnb[(i - 1) & 1];
        float* rn_w      = rnb[i & 1];
        const unsigned* p0o = phb[(i - 1) & 1];
        unsigned* p0n       = phb[i & 1];
        const float* Bo  = Bb[(i - 1) & 1];
        float* Bn        = Bb[i & 1];
        if (i < L_ - 1)
            hipLaunchKernelGGL((k_F<0, 1>), gA, blk, 0, stream,
                               img, rin, rn_w, p0o, p0n, Bo, Bn,
                               (const float2*)ss2, outp);
        else
            hipLaunchKernelGGL((k_F<0, 0>), gA, blk, 0, stream,
                               img, rin, rn_w, p0o, p0n, Bo, Bn,
                               (const float2*)ss2, outp);
    }
    (void)in_sizes; (void)n_in; (void)out_size;
}